// Round 6
// baseline (702.265 us; speedup 1.0000x reference)
//
#include <hip/hip_runtime.h>

typedef unsigned short u16;
typedef __attribute__((ext_vector_type(8))) short short8;
typedef __attribute__((ext_vector_type(4))) float f32x4;

#define B_   2
#define N_   5
#define K_   5
#define Q_   4
#define T_   5
#define D_   768
#define L_   128
#define BN_  (B_*N_)            // 10
#define BNK_ (B_*N_*K_)         // 50
#define BQ_  (B_*N_*Q_*N_)      // 200
#define K4_  (4*D_)             // 3072

#define QEMB_N  (40*128*768)    // 3,932,160
#define PROJW_N (768*3072)      // 2,359,296
#define G1ROWS  5248            // 40*128 query rows + 50 proto rows + pad

__device__ __forceinline__ float bf2f(u16 u) {
    return __uint_as_float(((unsigned)u) << 16);
}
__device__ __forceinline__ u16 f2bf(float f) {
    unsigned u = __float_as_uint(f);
    return (u16)((u + 0x7fffu + ((u >> 16) & 1u)) >> 16);
}
// swizzled unit within a 16x32 bf16 tile: g = k-octet 0..3, r = row 0..15
// write mapping (lanes ko-major) and read mapping (lanes row-major) are BOTH
// uniform 8-lanes-per-4-bank-group => conflict-free ds_write_b128/ds_read_b128.
#define SWZ(g, r) (((g) << 4) + ((r) ^ ((g) << 2)))

// ---------------- K0: convert qemb/projw/relw1 f32 -> bf16 ----------------
__global__ void k_convert3(const float* __restrict__ q, const float* __restrict__ pw,
                           const float* __restrict__ rw, u16* __restrict__ qo,
                           u16* __restrict__ po, u16* __restrict__ ro) {
    const long n1 = QEMB_N / 4, n2 = PROJW_N / 4;
    const long total = n1 + 2 * n2;
    for (long i = (long)blockIdx.x * 256 + threadIdx.x; i < total; i += (long)gridDim.x * 256) {
        const float* src; u16* dst; long k;
        if (i < n1)            { src = q;  dst = qo; k = i; }
        else if (i < n1 + n2)  { src = pw; dst = po; k = i - n1; }
        else                   { src = rw; dst = ro; k = i - n1 - n2; }
        float4 v = ((const float4*)src)[k];
        u16 o[4] = {f2bf(v.x), f2bf(v.y), f2bf(v.z), f2bf(v.w)};
        *(uint2*)(dst + k * 4) = *(const uint2*)o;
    }
}

// ---------------- K1: per-shot tag prototypes ----------------
__global__ void k_proto_shot(const float* __restrict__ label, const float* __restrict__ smask,
                             const float* __restrict__ semb, float* __restrict__ proto_shot) {
    int bnk = blockIdx.x;
    __shared__ int   s_tag[L_];
    __shared__ float s_w[L_];
    __shared__ float s_cnt[T_];
    int tid = threadIdx.x;
    if (tid < L_) {
        const float* lp = label + ((long)bnk * L_ + tid) * T_;
        float best = lp[0]; int bi = 0;
        #pragma unroll
        for (int t = 1; t < T_; ++t) { float v = lp[t]; if (v > best) { best = v; bi = t; } }
        s_tag[tid] = bi;
        s_w[tid]   = (bi == 0) ? smask[(long)bnk * L_ + tid] : 1.0f;
    }
    __syncthreads();
    if (tid < T_) {
        float c = 0.f;
        for (int l = 0; l < L_; ++l) if (s_tag[l] == tid) c += s_w[l];
        s_cnt[tid] = c;
    }
    __syncthreads();
    float acc[3][T_] = {};
    for (int l = 0; l < L_; ++l) {
        float w = s_w[l]; int tg = s_tag[l];
        const float* ep = semb + ((long)bnk * L_ + l) * D_;
        #pragma unroll
        for (int s = 0; s < 3; ++s) {
            float e = ep[tid + s * 256] * w;
            #pragma unroll
            for (int t = 0; t < T_; ++t) acc[s][t] += (tg == t) ? e : 0.0f;
        }
    }
    #pragma unroll
    for (int s = 0; s < 3; ++s) {
        int d = tid + s * 256;
        #pragma unroll
        for (int t = 0; t < T_; ++t) {
            float c = s_cnt[t];
            float v = (c > 0.f) ? acc[s][t] / fmaxf(c, 1.f) : 0.f;
            proto_shot[(bnk * T_ + t) * D_ + d] = v;
        }
    }
}

// ---------------- K1b: mean over K shots ----------------
__global__ void k_proto_mean(const float* __restrict__ proto_shot,
                             float* __restrict__ proto_f32, u16* __restrict__ proto_bf) {
    int idx = blockIdx.x * 256 + threadIdx.x;
    if (idx >= BN_ * T_ * D_) return;
    int bn = idx / (T_ * D_);
    int rem = idx - bn * (T_ * D_);
    float s = 0.f;
    #pragma unroll
    for (int k = 0; k < K_; ++k) s += proto_shot[(bn * K_ + k) * (T_ * D_) + rem];
    s *= (1.f / K_);
    proto_f32[idx] = s;
    proto_bf[idx]  = f2bf(s);
}

// ---------------- K2: co-attention -> es-fuse chunks 1..3 (bf16), p2m, qssum ----------------
__global__ void k_attn(const float* __restrict__ qemb, const float* __restrict__ qmask_g,
                       const float* __restrict__ proto_f32,
                       u16* __restrict__ esf, float* __restrict__ p2m_ws,
                       float* __restrict__ qssum_ws) {
    int bq = blockIdx.x;
    int q_idx = bq / N_;
    int bn = (bq / (N_ * Q_ * N_)) * N_ + (bq % N_);
    __shared__ float s_proto[T_ * D_];
    __shared__ float s_att[T_][L_];
    __shared__ float s_ps[T_][L_];
    __shared__ float s_qm[L_];
    int tid = threadIdx.x;
    for (int i = tid; i < T_ * D_; i += 256) s_proto[i] = proto_f32[bn * T_ * D_ + i];
    if (tid < L_) s_qm[tid] = qmask_g[(long)q_idx * L_ + tid];
    __syncthreads();
    for (int p = tid; p < T_ * L_; p += 256) {
        int t = p >> 7, q = p & (L_ - 1);
        const float* pp = s_proto + t * D_;
        const float4* qp = (const float4*)(qemb + ((size_t)q_idx * L_ + q) * D_);
        float acc = 0.f;
        #pragma unroll 4
        for (int d = 0; d < D_ / 4; ++d) {
            float4 v = qp[d];
            acc += v.x * pp[4 * d] + v.y * pp[4 * d + 1] + v.z * pp[4 * d + 2] + v.w * pp[4 * d + 3];
        }
        s_att[t][q] = acc + 100.f * s_qm[q];
    }
    __syncthreads();
    if (tid < T_) {                       // softmax over q (support path)
        int t = tid; float m = -1e30f;
        for (int q = 0; q < L_; ++q) m = fmaxf(m, s_att[t][q]);
        float ss = 0.f;
        for (int q = 0; q < L_; ++q) { float e = __expf(s_att[t][q] - m); s_ps[t][q] = e; ss += e; }
        float inv = 1.f / ss;
        for (int q = 0; q < L_; ++q) s_ps[t][q] *= inv;
    } else if (tid >= 128) {              // softmax over t (query path) -> masked weights
        int q = tid - 128; float m = -1e30f;
        float e[T_];
        #pragma unroll
        for (int t = 0; t < T_; ++t) m = fmaxf(m, s_att[t][q]);
        float ss = 0.f;
        #pragma unroll
        for (int t = 0; t < T_; ++t) { e[t] = __expf(s_att[t][q] - m); ss += e[t]; }
        float inv = s_qm[q] / ss;
        #pragma unroll
        for (int t = 0; t < T_; ++t) p2m_ws[((size_t)bq * T_ + t) * L_ + q] = e[t] * inv;
    } else if (tid == 5) {
        float s = 0.f;
        for (int q = 0; q < L_; ++q) s += s_qm[q];
        qssum_ws[bq] = s;
    }
    __syncthreads();
    {   // support_[t][d] then fuse chunks 1..3 (chunk 0 handled via G1)
        float acc[T_][3] = {};
        #pragma unroll 4
        for (int q = 0; q < L_; ++q) {
            const float* qp = qemb + ((size_t)q_idx * L_ + q) * D_;
            float qv[3];
            #pragma unroll
            for (int s = 0; s < 3; ++s) qv[s] = qp[tid + s * 256];
            #pragma unroll
            for (int t = 0; t < T_; ++t) {
                float p = s_ps[t][q];
                #pragma unroll
                for (int s = 0; s < 3; ++s) acc[t][s] += p * qv[s];
            }
        }
        #pragma unroll
        for (int t = 0; t < T_; ++t) {
            #pragma unroll
            for (int s = 0; s < 3; ++s) {
                int d = tid + s * 256;
                float p = s_proto[t * D_ + d];
                float sv = acc[t][s];
                size_t base = (((size_t)bq * T_ + t) * 4) * (size_t)D_ + d;
                esf[base + D_]       = f2bf(sv);
                esf[base + 2 * D_]   = f2bf(fabsf(p - sv));
                esf[base + 3 * D_]   = f2bf(p * sv);
            }
        }
    }
}

// ---------------- K3: G1 GEMM: [qemb(5120) ; proto(50) ; pad] @ W1^T -> bf16 ----------------
__global__ __launch_bounds__(256) void k_gemm_g1(const u16* __restrict__ qemb_bf,
                                                 const u16* __restrict__ proto_bf,
                                                 const u16* __restrict__ projw_bf,
                                                 u16* __restrict__ g1) {
    int mbase = blockIdx.y * 128;
    int jbase = blockIdx.x * 128;
    __shared__ __align__(16) u16 sA[8 * 512];
    __shared__ __align__(16) u16 sB[8 * 512];
    int tid = threadIdx.x;
    int lane = tid & 63, w = tid >> 6, quad = lane >> 4, l16 = lane & 15;
    f32x4 zero = {0.f, 0.f, 0.f, 0.f};
    f32x4 acc[8][2];
    #pragma unroll
    for (int rt = 0; rt < 8; ++rt) { acc[rt][0] = zero; acc[rt][1] = zero; }

    for (int kt = 0; kt < 24; ++kt) {
        int k0 = kt * 32;
        __syncthreads();
        #pragma unroll
        for (int j = 0; j < 2; ++j) {
            int v = tid + j * 256, row = v >> 2, g = v & 3;
            *(uint4*)(sB + (((row >> 4) << 6) + SWZ(g, row & 15)) * 8) =
                *(const uint4*)(projw_bf + (size_t)(jbase + row) * K4_ + k0 + g * 8);
            int grow = mbase + row;
            uint4 av = uint4{0u, 0u, 0u, 0u};
            if (grow < 5120)      av = *(const uint4*)(qemb_bf + (size_t)grow * D_ + k0 + g * 8);
            else if (grow < 5170) av = *(const uint4*)(proto_bf + (size_t)(grow - 5120) * D_ + k0 + g * 8);
            *(uint4*)(sA + (((row >> 4) << 6) + SWZ(g, row & 15)) * 8) = av;
        }
        __syncthreads();
        short8 af[8], bfr[2];
        #pragma unroll
        for (int rt = 0; rt < 8; ++rt)
            af[rt] = *(const short8*)(sA + ((rt << 6) + SWZ(quad, l16)) * 8);
        #pragma unroll
        for (int jj = 0; jj < 2; ++jj)
            bfr[jj] = *(const short8*)(sB + (((w * 2 + jj) << 6) + SWZ(quad, l16)) * 8);
        #pragma unroll
        for (int rt = 0; rt < 8; ++rt)
            #pragma unroll
            for (int jj = 0; jj < 2; ++jj)
                acc[rt][jj] = __builtin_amdgcn_mfma_f32_16x16x32_bf16(af[rt], bfr[jj], acc[rt][jj], 0, 0, 0);
    }
    #pragma unroll
    for (int jj = 0; jj < 2; ++jj) {
        int col = jbase + (w * 2 + jj) * 16 + l16;
        #pragma unroll
        for (int rt = 0; rt < 8; ++rt)
            #pragma unroll
            for (int r = 0; r < 4; ++r) {
                int row = mbase + rt * 16 + quad * 4 + r;
                g1[(size_t)row * D_ + col] = f2bf(acc[rt][jj][r]);
            }
    }
}

// ---------------- K4: fused main GEMM (K=2304, chunks 1..3) + G1 add + aggregation ----------------
// grid (6 jchunks of 128 cols, 200 bq), block 256. No register prefetch (spill-safe).
__global__ __launch_bounds__(256) void k_gemm_fused(
        const u16* __restrict__ qemb_bf, const float* __restrict__ p2m,
        const u16* __restrict__ proto_bf, const u16* __restrict__ esf,
        const u16* __restrict__ projw_bf, const float* __restrict__ projb,
        const u16* __restrict__ g1, const float* __restrict__ qssum_ws,
        u16* __restrict__ cat_ws) {
    int bq = blockIdx.y;
    int jbase = blockIdx.x * 128;
    int q_idx = bq / N_;
    int bn = (bq / (N_ * Q_ * N_)) * N_ + (bq % N_);
    __shared__ __align__(16) u16 sA[9 * 512];      // 9 swizzled 16x32 tiles
    __shared__ __align__(16) u16 sB[8 * 512];
    __shared__ __align__(16) u16 s_m2[128 * 32];   // query_ slab, plain [row][32]
    __shared__ __align__(16) float s_psf[T_ * 32]; // proto slab as f32
    __shared__ float s_p2m[T_ * 128];
    int tid = threadIdx.x;
    int lane = tid & 63, w = tid >> 6, quad = lane >> 4, l16 = lane & 15;

    for (int i = tid; i < 640; i += 256) s_p2m[i] = p2m[(size_t)bq * 640 + i];
    if (tid < 128) *(uint4*)(sA + 8 * 512 + tid * 8) = uint4{0u, 0u, 0u, 0u};  // zero es tile
    if (tid < 20) {   // proto slab 0 -> f32
        int t = tid >> 2, g = tid & 3;
        uint4 pv = *(const uint4*)(proto_bf + ((size_t)bn * T_ + t) * D_ + g * 8);
        const u16* ps = (const u16*)&pv;
        #pragma unroll
        for (int i = 0; i < 8; ++i) s_psf[t * 32 + g * 8 + i] = bf2f(ps[i]);
    }

    f32x4 zero = {0.f, 0.f, 0.f, 0.f};
    f32x4 acc[9][2];
    #pragma unroll
    for (int rt = 0; rt < 9; ++rt) { acc[rt][0] = zero; acc[rt][1] = zero; }

    for (int slab = 0; slab < 24; ++slab) {
        int d0 = slab * 32;
        #pragma unroll
        for (int ci = 0; ci < 3; ++ci) {
            int c = ci + 1;
            __syncthreads();
            // ---- stage B (128 cols x 32 k) ----
            #pragma unroll
            for (int j = 0; j < 2; ++j) {
                int v = tid + j * 256, row = v >> 2, g = v & 3;
                *(uint4*)(sB + (((row >> 4) << 6) + SWZ(g, row & 15)) * 8) =
                    *(const uint4*)(projw_bf + (size_t)(jbase + row) * K4_ + c * D_ + d0 + g * 8);
            }
            // ---- stage A query rows 0..127 ----
            #pragma unroll
            for (int j = 0; j < 2; ++j) {
                int u = tid + j * 256, row = u >> 2, g = u & 3;
                short8 val;
                if (c == 1) {
                    float p0 = s_p2m[row], p1 = s_p2m[128 + row], p2v = s_p2m[256 + row];
                    float p3 = s_p2m[384 + row], p4 = s_p2m[512 + row];
                    const float* f0 = s_psf + g * 8;
                    short8 o;
                    #pragma unroll
                    for (int i = 0; i < 8; ++i) {
                        float m2 = p0 * f0[i] + p1 * f0[32 + i] + p2v * f0[64 + i]
                                 + p3 * f0[96 + i] + p4 * f0[128 + i];
                        o[i] = (short)f2bf(m2);
                    }
                    *(short8*)(s_m2 + row * 32 + g * 8) = o;
                    val = o;
                } else {
                    short8 a = *(const short8*)(qemb_bf + ((size_t)q_idx * L_ + row) * D_ + d0 + g * 8);
                    short8 b = *(const short8*)(s_m2 + row * 32 + g * 8);
                    short8 o;
                    #pragma unroll
                    for (int i = 0; i < 8; ++i) {
                        float x = bf2f((u16)a[i]), y = bf2f((u16)b[i]);
                        float r = (c == 2) ? fabsf(x - y) : x * y;
                        o[i] = (short)f2bf(r);
                    }
                    val = o;
                }
                *(short8*)(sA + (((row >> 4) << 6) + SWZ(g, row & 15)) * 8) = val;
            }
            // ---- es rows (precomputed fuse) ----
            if (tid < 20) {
                int t = tid >> 2, g = tid & 3;
                *(uint4*)(sA + ((8 << 6) + SWZ(g, t)) * 8) =
                    *(const uint4*)(esf + ((((size_t)bq * T_ + t) * 4) + c) * (size_t)D_ + d0 + g * 8);
            }
            // ---- proto slab for next slab's c==1 (written at c==2, read after 3 barriers) ----
            if (c == 2 && slab + 1 < 24 && tid >= 32 && tid < 52) {
                int i2 = tid - 32, t = i2 >> 2, g = i2 & 3;
                uint4 pv = *(const uint4*)(proto_bf + ((size_t)bn * T_ + t) * D_ + d0 + 32 + g * 8);
                const u16* ps = (const u16*)&pv;
                #pragma unroll
                for (int i = 0; i < 8; ++i) s_psf[t * 32 + g * 8 + i] = bf2f(ps[i]);
            }
            __syncthreads();
            // ---- fragments + MFMA ----
            short8 af[9], bfr[2];
            #pragma unroll
            for (int rt = 0; rt < 9; ++rt)
                af[rt] = *(const short8*)(sA + ((rt << 6) + SWZ(quad, l16)) * 8);
            #pragma unroll
            for (int jj = 0; jj < 2; ++jj)
                bfr[jj] = *(const short8*)(sB + (((w * 2 + jj) << 6) + SWZ(quad, l16)) * 8);
            #pragma unroll
            for (int rt = 0; rt < 9; ++rt)
                #pragma unroll
                for (int jj = 0; jj < 2; ++jj)
                    acc[rt][jj] = __builtin_amdgcn_mfma_f32_16x16x32_bf16(af[rt], bfr[jj], acc[rt][jj], 0, 0, 0);
        }
    }
    // ---- epilogue: +G1 +bias, relu, reduce -> cat_seq[bq][4*768] ----
    float inv_qs = 1.f / qssum_ws[bq];
    #pragma unroll
    for (int jj = 0; jj < 2; ++jj) {
        int col = jbase + (w * 2 + jj) * 16 + l16;
        float bias = projb[col];
        float qmax = 0.f, qsum = 0.f, smax = 0.f, ssum = 0.f;
        #pragma unroll
        for (int rt = 0; rt < 8; ++rt) {
            #pragma unroll
            for (int r = 0; r < 4; ++r) {
                int row = rt * 16 + quad * 4 + r;
                float g1v = bf2f(g1[(size_t)(q_idx * 128 + row) * D_ + col]);
                float v = fmaxf(acc[rt][jj][r] + g1v + bias, 0.f);
                qmax = fmaxf(qmax, v); qsum += v;
            }
        }
        #pragma unroll
        for (int r = 0; r < 4; ++r) {
            int t = quad * 4 + r;
            if (t < T_) {
                float g1v = bf2f(g1[(size_t)(5120 + bn * T_ + t) * D_ + col]);
                float v = fmaxf(acc[8][jj][r] + g1v + bias, 0.f);
                smax = fmaxf(smax, v); ssum += v;
            }
        }
        qmax = fmaxf(qmax, __shfl_xor(qmax, 16, 64)); qmax = fmaxf(qmax, __shfl_xor(qmax, 32, 64));
        qsum += __shfl_xor(qsum, 16, 64);             qsum += __shfl_xor(qsum, 32, 64);
        smax = fmaxf(smax, __shfl_xor(smax, 16, 64)); smax = fmaxf(smax, __shfl_xor(smax, 32, 64));
        ssum += __shfl_xor(ssum, 16, 64);             ssum += __shfl_xor(ssum, 32, 64);
        if (quad == 0) {
            u16* cp = cat_ws + (size_t)bq * K4_;
            cp[col]           = f2bf(qmax);
            cp[D_ + col]      = f2bf(qsum * inv_qs);
            cp[2 * D_ + col]  = f2bf(smax);
            cp[3 * D_ + col]  = f2bf(ssum * 0.2f);
        }
    }
}

// ---------------- K5: relation MLP GEMM, split-K -> f32 partials ----------------
#define AST  40
__global__ __launch_bounds__(256) void k_relmlp(const u16* __restrict__ cat_ws,
                                                const u16* __restrict__ w1,
                                                float* __restrict__ part) {
    int mbase = blockIdx.y * 64;
    int jbase = blockIdx.x * 128;
    int ks = blockIdx.z;
    __shared__ __align__(16) u16 sA[64 * AST];
    __shared__ __align__(16) u16 sB[128 * AST];
    int tid = threadIdx.x;
    int lane = tid & 63, w = tid >> 6, quad = lane >> 4, l16 = lane & 15;
    f32x4 zero = {0.f, 0.f, 0.f, 0.f};
    f32x4 acc[4][2];
    #pragma unroll
    for (int rt = 0; rt < 4; ++rt) { acc[rt][0] = zero; acc[rt][1] = zero; }

    for (int kt = ks * 12; kt < ks * 12 + 12; ++kt) {
        int k0 = kt * 32;
        __syncthreads();
        {
            int row = tid >> 2, ko = (tid & 3) * 8;
            int grow = mbase + row;
            short8 val = short8{0, 0, 0, 0, 0, 0, 0, 0};
            if (grow < BQ_) val = *(const short8*)(cat_ws + (size_t)grow * K4_ + k0 + ko);
            *(short8*)(sA + row * AST + ko) = val;
        }
        for (int u = tid; u < 512; u += 256) {
            int row = u >> 2, ko = (u & 3) * 8;
            *(short8*)(sB + row * AST + ko) =
                *(const short8*)(w1 + (size_t)(jbase + row) * K4_ + k0 + ko);
        }
        __syncthreads();
        short8 af[4], bfr[2];
        #pragma unroll
        for (int rt = 0; rt < 4; ++rt)
            af[rt] = *(const short8*)(sA + (rt * 16 + l16) * AST + quad * 8);
        #pragma unroll
        for (int jj = 0; jj < 2; ++jj)
            bfr[jj] = *(const short8*)(sB + ((2 * w + jj) * 16 + l16) * AST + quad * 8);
        #pragma unroll
        for (int rt = 0; rt < 4; ++rt)
            #pragma unroll
            for (int jj = 0; jj < 2; ++jj)
                acc[rt][jj] = __builtin_amdgcn_mfma_f32_16x16x32_bf16(af[rt], bfr[jj], acc[rt][jj], 0, 0, 0);
    }
    #pragma unroll
    for (int jj = 0; jj < 2; ++jj) {
        int col = jbase + (2 * w + jj) * 16 + l16;
        #pragma unroll
        for (int rt = 0; rt < 4; ++rt) {
            #pragma unroll
            for (int r = 0; r < 4; ++r) {
                int grow = mbase + rt * 16 + quad * 4 + r;
                if (grow < BQ_)
                    part[((size_t)ks * BQ_ + grow) * D_ + col] = acc[rt][jj][r];
            }
        }
    }
}

// ---------------- K6: finish — sum partials, bias+relu, dot w2 (all f32) ----------------
__global__ void k_rel_fin(const float* __restrict__ part, const float* __restrict__ b1,
                          const float* __restrict__ w2, const float* __restrict__ b2,
                          float* __restrict__ out) {
    int bq = blockIdx.x, tid = threadIdx.x;
    float a = 0.f;
    #pragma unroll
    for (int s = 0; s < 3; ++s) {
        int col = tid + s * 256;
        float sum = 0.f;
        #pragma unroll
        for (int ks = 0; ks < 8; ++ks) sum += part[((size_t)ks * BQ_ + bq) * D_ + col];
        float h = fmaxf(sum + b1[col], 0.f);
        a += h * w2[col];
    }
    __shared__ float red[256];
    red[tid] = a; __syncthreads();
    for (int off = 128; off >= 1; off >>= 1) {
        if (tid < off) red[tid] += red[tid + off];
        __syncthreads();
    }
    if (tid == 0) out[bq] = red[0] + b2[0];
}

extern "C" void kernel_launch(void* const* d_in, const int* in_sizes, int n_in,
                              void* d_out, int out_size, void* d_ws, size_t ws_size,
                              hipStream_t stream) {
    (void)in_sizes; (void)n_in; (void)out_size; (void)ws_size;
    const float* semb  = (const float*)d_in[0];
    const float* qemb  = (const float*)d_in[1];
    const float* smask = (const float*)d_in[2];
    const float* qmask = (const float*)d_in[3];
    const float* label = (const float*)d_in[4];
    const float* projw = (const float*)d_in[5];
    const float* projb = (const float*)d_in[6];
    const float* relw1 = (const float*)d_in[7];
    const float* relb1 = (const float*)d_in[8];
    const float* relw2 = (const float*)d_in[9];
    const float* relb2 = (const float*)d_in[10];

    char* ws = (char*)d_ws;
    u16*   qemb_bf   = (u16*)  (ws + 0);           // 7,864,320
    u16*   projw_bf  = (u16*)  (ws + 7864320);     // 4,718,592
    u16*   relw1_bf  = (u16*)  (ws + 12582912);    // 4,718,592
    float* proto_shot= (float*)(ws + 17301504);    // 768,000
    float* proto_f32 = (float*)(ws + 18069504);    // 153,600
    u16*   proto_bf  = (u16*)  (ws + 18223104);    // 76,800
    u16*   esf_ws    = (u16*)  (ws + 18299904);    // 6,144,000
    float* p2m_ws    = (float*)(ws + 24443904);    // 512,000
    float* qssum     = (float*)(ws + 24955904);    // 896
    u16*   cat_ws    = (u16*)  (ws + 24956800);    // 1,228,800
    u16*   g1_ws     = (u16*)  (ws + 26185600);    // 5248*768*2 = 8,060,928
    float* part_ws   = (float*)(ws + 26185600);    // 4,915,200 — ALIASES g1 (dead after k_gemm_fused)
    // total 34,246,528 bytes (~34.2 MB)

    k_convert3<<<2048, 256, 0, stream>>>(qemb, projw, relw1, qemb_bf, projw_bf, relw1_bf);
    k_proto_shot<<<BNK_, 256, 0, stream>>>(label, smask, semb, proto_shot);
    k_proto_mean<<<150, 256, 0, stream>>>(proto_shot, proto_f32, proto_bf);
    k_attn<<<BQ_, 256, 0, stream>>>(qemb, qmask, proto_f32, esf_ws, p2m_ws, qssum);
    k_gemm_g1<<<dim3(6, 41), 256, 0, stream>>>(qemb_bf, proto_bf, projw_bf, g1_ws);
    k_gemm_fused<<<dim3(6, BQ_), 256, 0, stream>>>(qemb_bf, p2m_ws, proto_bf, esf_ws,
                                                   projw_bf, projb, g1_ws, qssum, cat_ws);
    k_relmlp<<<dim3(6, 4, 8), 256, 0, stream>>>(cat_ws, relw1_bf, part_ws);
    k_rel_fin<<<BQ_, 256, 0, stream>>>(part_ws, relb1, relw2, relb2, (float*)d_out);
}

// Round 7
// 567.542 us; speedup vs baseline: 1.2374x; 1.2374x over previous
//
#include <hip/hip_runtime.h>

typedef unsigned short u16;
typedef __attribute__((ext_vector_type(8))) short short8;
typedef __attribute__((ext_vector_type(4))) float f32x4;

#define B_   2
#define N_   5
#define K_   5
#define Q_   4
#define T_   5
#define D_   768
#define L_   128
#define BN_  (B_*N_)            // 10
#define BNK_ (B_*N_*K_)         // 50
#define BQ_  (B_*N_*Q_*N_)      // 200
#define K4_  (4*D_)             // 3072
#define KF   2304               // fuse K (chunks 1..3)
#define AROWS 144               // 128 query + 5 es + 11 pad

#define QEMB_N  (40*128*768)    // 3,932,160
#define PROJW_N (768*3072)      // 2,359,296

__device__ __forceinline__ float bf2f(u16 u) {
    return __uint_as_float(((unsigned)u) << 16);
}
__device__ __forceinline__ u16 f2bf(float f) {
    unsigned u = __float_as_uint(f);
    return (u16)((u + 0x7fffu + ((u >> 16) & 1u)) >> 16);
}
// async global->LDS, 16B per lane; lds base must be wave-uniform (HW adds lane*16)
__device__ __forceinline__ void gl_lds16(const u16* g, u16* l) {
    __builtin_amdgcn_global_load_lds(
        (const __attribute__((address_space(1))) unsigned int*)g,
        (__attribute__((address_space(3))) unsigned int*)l, 16, 0, 0);
}

// ---------------- K0: convert qemb/projw/relw1 f32 -> bf16 ----------------
__global__ void k_convert3(const float* __restrict__ q, const float* __restrict__ pw,
                           const float* __restrict__ rw, u16* __restrict__ qo,
                           u16* __restrict__ po, u16* __restrict__ ro) {
    const long n1 = QEMB_N / 4, n2 = PROJW_N / 4;
    const long total = n1 + 2 * n2;
    for (long i = (long)blockIdx.x * 256 + threadIdx.x; i < total; i += (long)gridDim.x * 256) {
        const float* src; u16* dst; long k;
        if (i < n1)            { src = q;  dst = qo; k = i; }
        else if (i < n1 + n2)  { src = pw; dst = po; k = i - n1; }
        else                   { src = rw; dst = ro; k = i - n1 - n2; }
        float4 v = ((const float4*)src)[k];
        u16 o[4] = {f2bf(v.x), f2bf(v.y), f2bf(v.z), f2bf(v.w)};
        *(uint2*)(dst + k * 4) = *(const uint2*)o;
    }
}

// ---------------- K1: per-shot tag prototypes ----------------
__global__ void k_proto_shot(const float* __restrict__ label, const float* __restrict__ smask,
                             const float* __restrict__ semb, float* __restrict__ proto_shot) {
    int bnk = blockIdx.x;
    __shared__ int   s_tag[L_];
    __shared__ float s_w[L_];
    __shared__ float s_cnt[T_];
    int tid = threadIdx.x;
    if (tid < L_) {
        const float* lp = label + ((long)bnk * L_ + tid) * T_;
        float best = lp[0]; int bi = 0;
        #pragma unroll
        for (int t = 1; t < T_; ++t) { float v = lp[t]; if (v > best) { best = v; bi = t; } }
        s_tag[tid] = bi;
        s_w[tid]   = (bi == 0) ? smask[(long)bnk * L_ + tid] : 1.0f;
    }
    __syncthreads();
    if (tid < T_) {
        float c = 0.f;
        for (int l = 0; l < L_; ++l) if (s_tag[l] == tid) c += s_w[l];
        s_cnt[tid] = c;
    }
    __syncthreads();
    float acc[3][T_] = {};
    for (int l = 0; l < L_; ++l) {
        float w = s_w[l]; int tg = s_tag[l];
        const float* ep = semb + ((long)bnk * L_ + l) * D_;
        #pragma unroll
        for (int s = 0; s < 3; ++s) {
            float e = ep[tid + s * 256] * w;
            #pragma unroll
            for (int t = 0; t < T_; ++t) acc[s][t] += (tg == t) ? e : 0.0f;
        }
    }
    #pragma unroll
    for (int s = 0; s < 3; ++s) {
        int d = tid + s * 256;
        #pragma unroll
        for (int t = 0; t < T_; ++t) {
            float c = s_cnt[t];
            float v = (c > 0.f) ? acc[s][t] / fmaxf(c, 1.f) : 0.f;
            proto_shot[(bnk * T_ + t) * D_ + d] = v;
        }
    }
}

// ---------------- K1b: mean over K shots ----------------
__global__ void k_proto_mean(const float* __restrict__ proto_shot,
                             float* __restrict__ proto_f32, u16* __restrict__ proto_bf) {
    int idx = blockIdx.x * 256 + threadIdx.x;
    if (idx >= BN_ * T_ * D_) return;
    int bn = idx / (T_ * D_);
    int rem = idx - bn * (T_ * D_);
    float s = 0.f;
    #pragma unroll
    for (int k = 0; k < K_; ++k) s += proto_shot[(bn * K_ + k) * (T_ * D_) + rem];
    s *= (1.f / K_);
    proto_f32[idx] = s;
    proto_bf[idx]  = f2bf(s);
}

// ---------------- K2: co-attention -> full fuse-row matrix qf (chunks 1..3), qssum ----------------
__global__ void k_attn(const float* __restrict__ qemb, const float* __restrict__ qmask_g,
                       const float* __restrict__ proto_f32,
                       u16* __restrict__ qf, float* __restrict__ qssum_ws) {
    int bq = blockIdx.x;
    int q_idx = bq / N_;
    int bn = (bq / (N_ * Q_ * N_)) * N_ + (bq % N_);
    __shared__ float s_proto[T_ * D_];
    __shared__ float s_att[T_][L_];
    __shared__ float s_ps[T_][L_];
    __shared__ float s_p2[L_][8];
    __shared__ float s_qm[L_];
    int tid = threadIdx.x;
    for (int i = tid; i < T_ * D_; i += 256) s_proto[i] = proto_f32[bn * T_ * D_ + i];
    if (tid < L_) s_qm[tid] = qmask_g[(long)q_idx * L_ + tid];
    __syncthreads();
    for (int p = tid; p < T_ * L_; p += 256) {
        int t = p >> 7, q = p & (L_ - 1);
        const float* pp = s_proto + t * D_;
        const float4* qp = (const float4*)(qemb + ((size_t)q_idx * L_ + q) * D_);
        float acc = 0.f;
        #pragma unroll 4
        for (int d = 0; d < D_ / 4; ++d) {
            float4 v = qp[d];
            acc += v.x * pp[4 * d] + v.y * pp[4 * d + 1] + v.z * pp[4 * d + 2] + v.w * pp[4 * d + 3];
        }
        s_att[t][q] = acc + 100.f * s_qm[q];
    }
    __syncthreads();
    if (tid < T_) {                       // softmax over q (support path)
        int t = tid; float m = -1e30f;
        for (int q = 0; q < L_; ++q) m = fmaxf(m, s_att[t][q]);
        float ss = 0.f;
        for (int q = 0; q < L_; ++q) { float e = __expf(s_att[t][q] - m); s_ps[t][q] = e; ss += e; }
        float inv = 1.f / ss;
        for (int q = 0; q < L_; ++q) s_ps[t][q] *= inv;
    } else if (tid >= 128) {              // softmax over t (query path) -> masked weights in LDS
        int q = tid - 128; float m = -1e30f;
        float e[T_];
        #pragma unroll
        for (int t = 0; t < T_; ++t) m = fmaxf(m, s_att[t][q]);
        float ss = 0.f;
        #pragma unroll
        for (int t = 0; t < T_; ++t) { e[t] = __expf(s_att[t][q] - m); ss += e[t]; }
        float inv = s_qm[q] / ss;
        #pragma unroll
        for (int t = 0; t < T_; ++t) s_p2[q][t] = e[t] * inv;
    } else if (tid == 5) {
        float s = 0.f;
        for (int q = 0; q < L_; ++q) s += s_qm[q];
        qssum_ws[bq] = s;
    }
    __syncthreads();
    u16* qfb = qf + (size_t)bq * AROWS * KF;
    {   // support_[t][d] -> es fuse rows 128..132 (chunks 1..3), f32 math
        float acc[T_][3] = {};
        #pragma unroll 4
        for (int q = 0; q < L_; ++q) {
            const float* qp = qemb + ((size_t)q_idx * L_ + q) * D_;
            float qv[3];
            #pragma unroll
            for (int s = 0; s < 3; ++s) qv[s] = qp[tid + s * 256];
            #pragma unroll
            for (int t = 0; t < T_; ++t) {
                float p = s_ps[t][q];
                #pragma unroll
                for (int s = 0; s < 3; ++s) acc[t][s] += p * qv[s];
            }
        }
        #pragma unroll
        for (int t = 0; t < T_; ++t) {
            u16* er = qfb + (128 + t) * KF;
            #pragma unroll
            for (int s = 0; s < 3; ++s) {
                int d = tid + s * 256;
                float p = s_proto[t * D_ + d];
                float sv = acc[t][s];
                er[d]            = f2bf(sv);
                er[768 + d]      = f2bf(fabsf(p - sv));
                er[1536 + d]     = f2bf(p * sv);
            }
        }
    }
    {   // query fuse rows 0..127: thread (q = tid>>1, h = tid&1) covers 384 cols
        int q = tid >> 1, h = tid & 1;
        float wt[T_];
        #pragma unroll
        for (int t = 0; t < T_; ++t) wt[t] = s_p2[q][t];
        const float* qrow = qemb + ((size_t)q_idx * L_ + q) * D_ + h * 384;
        u16* qr = qfb + q * KF + h * 384;
        for (int oct = 0; oct < 48; ++oct) {
            int d = h * 384 + oct * 8;
            float4 v0 = *(const float4*)(qrow + oct * 8);
            float4 v1 = *(const float4*)(qrow + oct * 8 + 4);
            float qv[8] = {v0.x, v0.y, v0.z, v0.w, v1.x, v1.y, v1.z, v1.w};
            float m2[8] = {0, 0, 0, 0, 0, 0, 0, 0};
            #pragma unroll
            for (int t = 0; t < T_; ++t) {
                float4 p0 = *(const float4*)(s_proto + t * D_ + d);
                float4 p1 = *(const float4*)(s_proto + t * D_ + d + 4);
                float w = wt[t];
                m2[0] += w * p0.x; m2[1] += w * p0.y; m2[2] += w * p0.z; m2[3] += w * p0.w;
                m2[4] += w * p1.x; m2[5] += w * p1.y; m2[6] += w * p1.z; m2[7] += w * p1.w;
            }
            short8 o1, o2, o3;
            #pragma unroll
            for (int i = 0; i < 8; ++i) {
                o1[i] = (short)f2bf(m2[i]);
                o2[i] = (short)f2bf(fabsf(qv[i] - m2[i]));
                o3[i] = (short)f2bf(qv[i] * m2[i]);
            }
            *(short8*)(qr + oct * 8)        = o1;
            *(short8*)(qr + 768 + oct * 8)  = o2;
            *(short8*)(qr + 1536 + oct * 8) = o3;
        }
    }
    {   // zero pad rows 133..143
        u16* pr = qfb + 133 * KF;
        short8 z = short8{0, 0, 0, 0, 0, 0, 0, 0};
        for (int i = tid; i < (11 * KF) / 8; i += 256) *(short8*)(pr + i * 8) = z;
    }
}

// ---------------- K3: G1 GEMM: [qemb(5120) ; proto(50) ; pad] @ W1c0^T -> bf16 ----------------
#define SWZ(g, r) (((g) << 4) + ((r) ^ ((g) << 2)))
__global__ __launch_bounds__(256) void k_gemm_g1(const u16* __restrict__ qemb_bf,
                                                 const u16* __restrict__ proto_bf,
                                                 const u16* __restrict__ projw_bf,
                                                 u16* __restrict__ g1) {
    int mbase = blockIdx.y * 128;
    int jbase = blockIdx.x * 128;
    __shared__ __align__(16) u16 sA[8 * 512];
    __shared__ __align__(16) u16 sB[8 * 512];
    int tid = threadIdx.x;
    int lane = tid & 63, w = tid >> 6, quad = lane >> 4, l16 = lane & 15;
    f32x4 zero = {0.f, 0.f, 0.f, 0.f};
    f32x4 acc[8][2];
    #pragma unroll
    for (int rt = 0; rt < 8; ++rt) { acc[rt][0] = zero; acc[rt][1] = zero; }

    for (int kt = 0; kt < 24; ++kt) {
        int k0 = kt * 32;
        __syncthreads();
        #pragma unroll
        for (int j = 0; j < 2; ++j) {
            int v = tid + j * 256, row = v >> 2, g = v & 3;
            *(uint4*)(sB + (((row >> 4) << 6) + SWZ(g, row & 15)) * 8) =
                *(const uint4*)(projw_bf + (size_t)(jbase + row) * K4_ + k0 + g * 8);
            int grow = mbase + row;
            uint4 av = uint4{0u, 0u, 0u, 0u};
            if (grow < 5120)      av = *(const uint4*)(qemb_bf + (size_t)grow * D_ + k0 + g * 8);
            else if (grow < 5170) av = *(const uint4*)(proto_bf + (size_t)(grow - 5120) * D_ + k0 + g * 8);
            *(uint4*)(sA + (((row >> 4) << 6) + SWZ(g, row & 15)) * 8) = av;
        }
        __syncthreads();
        short8 af[8], bfr[2];
        #pragma unroll
        for (int rt = 0; rt < 8; ++rt)
            af[rt] = *(const short8*)(sA + ((rt << 6) + SWZ(quad, l16)) * 8);
        #pragma unroll
        for (int jj = 0; jj < 2; ++jj)
            bfr[jj] = *(const short8*)(sB + (((w * 2 + jj) << 6) + SWZ(quad, l16)) * 8);
        #pragma unroll
        for (int rt = 0; rt < 8; ++rt)
            #pragma unroll
            for (int jj = 0; jj < 2; ++jj)
                acc[rt][jj] = __builtin_amdgcn_mfma_f32_16x16x32_bf16(af[rt], bfr[jj], acc[rt][jj], 0, 0, 0);
    }
    #pragma unroll
    for (int jj = 0; jj < 2; ++jj) {
        int col = jbase + (w * 2 + jj) * 16 + l16;
        #pragma unroll
        for (int rt = 0; rt < 8; ++rt)
            #pragma unroll
            for (int r = 0; r < 4; ++r) {
                int row = mbase + rt * 16 + quad * 4 + r;
                g1[(size_t)row * D_ + col] = f2bf(acc[rt][jj][r]);
            }
    }
}

// ---------------- K4: main GEMM (m97-style, global_load_lds) + G1 add + aggregation ----------------
// grid (x=200 bq, y=6 j128) so a bq's j-blocks share an XCD. A = qf[bq] (144x2304),
// B = projw_bf cols, k-offset 768 (chunks 1..3), row stride 3072.
__global__ __launch_bounds__(256) void k_gemm_q(
        const u16* __restrict__ qf, const u16* __restrict__ projw_bf,
        const float* __restrict__ projb, const u16* __restrict__ g1,
        const float* __restrict__ qssum_ws, u16* __restrict__ cat_ws) {
    int bq = blockIdx.x;
    int jbase = blockIdx.y * 128;
    int q_idx = bq / N_;
    int bn = (bq / (N_ * Q_ * N_)) * N_ + (bq % N_);
    __shared__ __align__(16) u16 sA[AROWS * 32];
    __shared__ __align__(16) u16 sB[128 * 32];
    int tid = threadIdx.x;
    int lane = tid & 63, w = tid >> 6, quad = lane >> 4, l16 = lane & 15;
    int srow = lane >> 2, sko = lane & 3;          // staging: lane -> (row, k-octet)
    const u16* Ab = qf + (size_t)bq * AROWS * KF + (size_t)srow * KF + sko * 8;
    const u16* Bb = projw_bf + (size_t)jbase * K4_ + 768 + (size_t)srow * K4_ + sko * 8;
    u16* lA0 = sA + (w * 16) * 32;
    u16* lA1 = sA + (64 + w * 16) * 32;
    u16* lA2 = sA + 128 * 32;                      // wave 0 only
    u16* lB0 = sB + (w * 16) * 32;
    u16* lB1 = sB + (64 + w * 16) * 32;

    f32x4 zero = {0.f, 0.f, 0.f, 0.f};
    f32x4 acc[9][2];
    #pragma unroll
    for (int rt = 0; rt < 9; ++rt) { acc[rt][0] = zero; acc[rt][1] = zero; }

    for (int kt = 0; kt < KF / 32; ++kt) {
        int k0 = kt * 32;
        __syncthreads();
        gl_lds16(Ab + (size_t)(w * 16) * KF + k0, lA0);
        gl_lds16(Ab + (size_t)(64 + w * 16) * KF + k0, lA1);
        if (w == 0) gl_lds16(Ab + (size_t)128 * KF + k0, lA2);
        gl_lds16(Bb + (size_t)(w * 16) * K4_ + k0, lB0);
        gl_lds16(Bb + (size_t)(64 + w * 16) * K4_ + k0, lB1);
        __syncthreads();
        short8 af[9], bfr[2];
        #pragma unroll
        for (int rt = 0; rt < 9; ++rt)
            af[rt] = *(const short8*)(sA + (rt * 16 + l16) * 32 + quad * 8);
        #pragma unroll
        for (int jj = 0; jj < 2; ++jj)
            bfr[jj] = *(const short8*)(sB + ((w * 2 + jj) * 16 + l16) * 32 + quad * 8);
        #pragma unroll
        for (int rt = 0; rt < 9; ++rt)
            #pragma unroll
            for (int jj = 0; jj < 2; ++jj)
                acc[rt][jj] = __builtin_amdgcn_mfma_f32_16x16x32_bf16(af[rt], bfr[jj], acc[rt][jj], 0, 0, 0);
    }
    // epilogue: +G1 +bias, relu, reduce -> cat_seq[bq][4*768]
    float inv_qs = 1.f / qssum_ws[bq];
    #pragma unroll
    for (int jj = 0; jj < 2; ++jj) {
        int col = jbase + (w * 2 + jj) * 16 + l16;
        float bias = projb[col];
        float qmax = 0.f, qsum = 0.f, smax = 0.f, ssum = 0.f;
        #pragma unroll
        for (int rt = 0; rt < 8; ++rt) {
            #pragma unroll
            for (int r = 0; r < 4; ++r) {
                int row = rt * 16 + quad * 4 + r;
                float g1v = bf2f(g1[(size_t)(q_idx * 128 + row) * D_ + col]);
                float v = fmaxf(acc[rt][jj][r] + g1v + bias, 0.f);
                qmax = fmaxf(qmax, v); qsum += v;
            }
        }
        #pragma unroll
        for (int r = 0; r < 4; ++r) {
            int t = quad * 4 + r;
            if (t < T_) {
                float g1v = bf2f(g1[(size_t)(5120 + bn * T_ + t) * D_ + col]);
                float v = fmaxf(acc[8][jj][r] + g1v + bias, 0.f);
                smax = fmaxf(smax, v); ssum += v;
            }
        }
        qmax = fmaxf(qmax, __shfl_xor(qmax, 16, 64)); qmax = fmaxf(qmax, __shfl_xor(qmax, 32, 64));
        qsum += __shfl_xor(qsum, 16, 64);             qsum += __shfl_xor(qsum, 32, 64);
        smax = fmaxf(smax, __shfl_xor(smax, 16, 64)); smax = fmaxf(smax, __shfl_xor(smax, 32, 64));
        ssum += __shfl_xor(ssum, 16, 64);             ssum += __shfl_xor(ssum, 32, 64);
        if (quad == 0) {
            u16* cp = cat_ws + (size_t)bq * K4_;
            cp[col]           = f2bf(qmax);
            cp[D_ + col]      = f2bf(qsum * inv_qs);
            cp[2 * D_ + col]  = f2bf(smax);
            cp[3 * D_ + col]  = f2bf(ssum * 0.2f);
        }
    }
}

// ---------------- K5: relation MLP GEMM, split-K -> f32 partials ----------------
#define AST  40
__global__ __launch_bounds__(256) void k_relmlp(const u16* __restrict__ cat_ws,
                                                const u16* __restrict__ w1,
                                                float* __restrict__ part) {
    int mbase = blockIdx.y * 64;
    int jbase = blockIdx.x * 128;
    int ks = blockIdx.z;
    __shared__ __align__(16) u16 sA[64 * AST];
    __shared__ __align__(16) u16 sB[128 * AST];
    int tid = threadIdx.x;
    int lane = tid & 63, w = tid >> 6, quad = lane >> 4, l16 = lane & 15;
    f32x4 zero = {0.f, 0.f, 0.f, 0.f};
    f32x4 acc[4][2];
    #pragma unroll
    for (int rt = 0; rt < 4; ++rt) { acc[rt][0] = zero; acc[rt][1] = zero; }

    for (int kt = ks * 12; kt < ks * 12 + 12; ++kt) {
        int k0 = kt * 32;
        __syncthreads();
        {
            int row = tid >> 2, ko = (tid & 3) * 8;
            int grow = mbase + row;
            short8 val = short8{0, 0, 0, 0, 0, 0, 0, 0};
            if (grow < BQ_) val = *(const short8*)(cat_ws + (size_t)grow * K4_ + k0 + ko);
            *(short8*)(sA + row * AST + ko) = val;
        }
        for (int u = tid; u < 512; u += 256) {
            int row = u >> 2, ko = (u & 3) * 8;
            *(short8*)(sB + row * AST + ko) =
                *(const short8*)(w1 + (size_t)(jbase + row) * K4_ + k0 + ko);
        }
        __syncthreads();
        short8 af[4], bfr[2];
        #pragma unroll
        for (int rt = 0; rt < 4; ++rt)
            af[rt] = *(const short8*)(sA + (rt * 16 + l16) * AST + quad * 8);
        #pragma unroll
        for (int jj = 0; jj < 2; ++jj)
            bfr[jj] = *(const short8*)(sB + ((2 * w + jj) * 16 + l16) * AST + quad * 8);
        #pragma unroll
        for (int rt = 0; rt < 4; ++rt)
            #pragma unroll
            for (int jj = 0; jj < 2; ++jj)
                acc[rt][jj] = __builtin_amdgcn_mfma_f32_16x16x32_bf16(af[rt], bfr[jj], acc[rt][jj], 0, 0, 0);
    }
    #pragma unroll
    for (int jj = 0; jj < 2; ++jj) {
        int col = jbase + (2 * w + jj) * 16 + l16;
        #pragma unroll
        for (int rt = 0; rt < 4; ++rt) {
            #pragma unroll
            for (int r = 0; r < 4; ++r) {
                int grow = mbase + rt * 16 + quad * 4 + r;
                if (grow < BQ_)
                    part[((size_t)ks * BQ_ + grow) * D_ + col] = acc[rt][jj][r];
            }
        }
    }
}

// ---------------- K6: finish — sum partials, bias+relu, dot w2 (all f32) ----------------
__global__ void k_rel_fin(const float* __restrict__ part, const float* __restrict__ b1,
                          const float* __restrict__ w2, const float* __restrict__ b2,
                          float* __restrict__ out) {
    int bq = blockIdx.x, tid = threadIdx.x;
    float a = 0.f;
    #pragma unroll
    for (int s = 0; s < 3; ++s) {
        int col = tid + s * 256;
        float sum = 0.f;
        #pragma unroll
        for (int ks = 0; ks < 8; ++ks) sum += part[((size_t)ks * BQ_ + bq) * D_ + col];
        float h = fmaxf(sum + b1[col], 0.f);
        a += h * w2[col];
    }
    __shared__ float red[256];
    red[tid] = a; __syncthreads();
    for (int off = 128; off >= 1; off >>= 1) {
        if (tid < off) red[tid] += red[tid + off];
        __syncthreads();
    }
    if (tid == 0) out[bq] = red[0] + b2[0];
}

extern "C" void kernel_launch(void* const* d_in, const int* in_sizes, int n_in,
                              void* d_out, int out_size, void* d_ws, size_t ws_size,
                              hipStream_t stream) {
    (void)in_sizes; (void)n_in; (void)out_size; (void)ws_size;
    const float* semb  = (const float*)d_in[0];
    const float* qemb  = (const float*)d_in[1];
    const float* smask = (const float*)d_in[2];
    const float* qmask = (const float*)d_in[3];
    const float* label = (const float*)d_in[4];
    const float* projw = (const float*)d_in[5];
    const float* projb = (const float*)d_in[6];
    const float* relw1 = (const float*)d_in[7];
    const float* relb1 = (const float*)d_in[8];
    const float* relw2 = (const float*)d_in[9];
    const float* relb2 = (const float*)d_in[10];

    char* ws = (char*)d_ws;
    u16*   qemb_bf   = (u16*)  (ws + 0);           // 7,864,320
    u16*   projw_bf  = (u16*)  (ws + 7864320);     // 4,718,592
    u16*   relw1_bf  = (u16*)  (ws + 12582912);    // 4,718,592
    float* proto_shot= (float*)(ws + 17301504);    // 768,000
    float* proto_f32 = (float*)(ws + 18069504);    // 153,600
    u16*   proto_bf  = (u16*)  (ws + 18223104);    // 76,800
    float* qssum     = (float*)(ws + 18299904);    // 896
    u16*   cat_ws    = (u16*)  (ws + 18300800);    // 1,228,800
    u16*   g1_ws     = (u16*)  (ws + 19529600);    // 5248*768*2 = 8,060,928
    float* part_ws   = (float*)(ws + 19529600);    // aliases g1 (dead after k_gemm_q)
    u16*   qf_ws     = (u16*)  (ws + 27590528);    // 200*144*2304*2 = 132,710,400
    // total 160,300,928 bytes (~160.3 MB)

    k_convert3<<<2048, 256, 0, stream>>>(qemb, projw, relw1, qemb_bf, projw_bf, relw1_bf);
    k_proto_shot<<<BNK_, 256, 0, stream>>>(label, smask, semb, proto_shot);
    k_proto_mean<<<150, 256, 0, stream>>>(proto_shot, proto_f32, proto_bf);
    k_attn<<<BQ_, 256, 0, stream>>>(qemb, qmask, proto_f32, qf_ws, qssum);
    k_gemm_g1<<<dim3(6, 41), 256, 0, stream>>>(qemb_bf, proto_bf, projw_bf, g1_ws);
    k_gemm_q<<<dim3(BQ_, 6), 256, 0, stream>>>(qf_ws, projw_bf, projb, g1_ws, qssum, cat_ws);
    k_relmlp<<<dim3(6, 4, 8), 256, 0, stream>>>(cat_ws, relw1_bf, part_ws);
    k_rel_fin<<<BQ_, 256, 0, stream>>>(part_ws, relb1, relw2, relb2, (float*)d_out);
}

// Round 8
// 536.644 us; speedup vs baseline: 1.3086x; 1.0576x over previous
//
#include <hip/hip_runtime.h>

typedef unsigned short u16;
typedef __attribute__((ext_vector_type(8))) short short8;
typedef __attribute__((ext_vector_type(4))) float f32x4;

#define B_   2
#define N_   5
#define K_   5
#define Q_   4
#define T_   5
#define D_   768
#define L_   128
#define BN_  (B_*N_)            // 10
#define BNK_ (B_*N_*K_)         // 50
#define BQ_  (B_*N_*Q_*N_)      // 200
#define K4_  (4*D_)             // 3072
#define KFQ  1536               // fuse K in main GEMM (chunks 2,3 only)
#define AROWS 144               // 128 query + 5 es + 11 pad

#define QEMB_N  (40*128*768)    // 3,932,160
#define PROJW_N (768*3072)      // 2,359,296

__device__ __forceinline__ float bf2f(u16 u) {
    return __uint_as_float(((unsigned)u) << 16);
}
__device__ __forceinline__ u16 f2bf(float f) {
    unsigned u = __float_as_uint(f);
    return (u16)((u + 0x7fffu + ((u >> 16) & 1u)) >> 16);
}
// async global->LDS, 16B per lane; lds base wave-uniform (HW adds lane*16)
__device__ __forceinline__ void gl_lds16(const u16* g, u16* l) {
    __builtin_amdgcn_global_load_lds(
        (const __attribute__((address_space(1))) unsigned int*)g,
        (__attribute__((address_space(3))) unsigned int*)l, 16, 0, 0);
}

// ---------------- K0: convert qemb/projw/relw1 f32 -> bf16 ----------------
__global__ void k_convert3(const float* __restrict__ q, const float* __restrict__ pw,
                           const float* __restrict__ rw, u16* __restrict__ qo,
                           u16* __restrict__ po, u16* __restrict__ ro) {
    const long n1 = QEMB_N / 4, n2 = PROJW_N / 4;
    const long total = n1 + 2 * n2;
    for (long i = (long)blockIdx.x * 256 + threadIdx.x; i < total; i += (long)gridDim.x * 256) {
        const float* src; u16* dst; long k;
        if (i < n1)            { src = q;  dst = qo; k = i; }
        else if (i < n1 + n2)  { src = pw; dst = po; k = i - n1; }
        else                   { src = rw; dst = ro; k = i - n1 - n2; }
        float4 v = ((const float4*)src)[k];
        u16 o[4] = {f2bf(v.x), f2bf(v.y), f2bf(v.z), f2bf(v.w)};
        *(uint2*)(dst + k * 4) = *(const uint2*)o;
    }
}

// ---------------- K1: per-shot tag prototypes ----------------
__global__ void k_proto_shot(const float* __restrict__ label, const float* __restrict__ smask,
                             const float* __restrict__ semb, float* __restrict__ proto_shot) {
    int bnk = blockIdx.x;
    __shared__ int   s_tag[L_];
    __shared__ float s_w[L_];
    __shared__ float s_cnt[T_];
    int tid = threadIdx.x;
    if (tid < L_) {
        const float* lp = label + ((long)bnk * L_ + tid) * T_;
        float best = lp[0]; int bi = 0;
        #pragma unroll
        for (int t = 1; t < T_; ++t) { float v = lp[t]; if (v > best) { best = v; bi = t; } }
        s_tag[tid] = bi;
        s_w[tid]   = (bi == 0) ? smask[(long)bnk * L_ + tid] : 1.0f;
    }
    __syncthreads();
    if (tid < T_) {
        float c = 0.f;
        for (int l = 0; l < L_; ++l) if (s_tag[l] == tid) c += s_w[l];
        s_cnt[tid] = c;
    }
    __syncthreads();
    float acc[3][T_] = {};
    for (int l = 0; l < L_; ++l) {
        float w = s_w[l]; int tg = s_tag[l];
        const float* ep = semb + ((long)bnk * L_ + l) * D_;
        #pragma unroll
        for (int s = 0; s < 3; ++s) {
            float e = ep[tid + s * 256] * w;
            #pragma unroll
            for (int t = 0; t < T_; ++t) acc[s][t] += (tg == t) ? e : 0.0f;
        }
    }
    #pragma unroll
    for (int s = 0; s < 3; ++s) {
        int d = tid + s * 256;
        #pragma unroll
        for (int t = 0; t < T_; ++t) {
            float c = s_cnt[t];
            float v = (c > 0.f) ? acc[s][t] / fmaxf(c, 1.f) : 0.f;
            proto_shot[(bnk * T_ + t) * D_ + d] = v;
        }
    }
}

// ---------------- K1b: mean over K shots ----------------
__global__ void k_proto_mean(const float* __restrict__ proto_shot,
                             float* __restrict__ proto_f32, u16* __restrict__ proto_bf) {
    int idx = blockIdx.x * 256 + threadIdx.x;
    if (idx >= BN_ * T_ * D_) return;
    int bn = idx / (T_ * D_);
    int rem = idx - bn * (T_ * D_);
    float s = 0.f;
    #pragma unroll
    for (int k = 0; k < K_; ++k) s += proto_shot[(bn * K_ + k) * (T_ * D_) + rem];
    s *= (1.f / K_);
    proto_f32[idx] = s;
    proto_bf[idx]  = f2bf(s);
}

// ---------------- K2: co-attention -> qf (chunks 2,3), sup, p2m, qssum ----------------
// block swizzle: 5 bq sharing a q_idx land on the same XCD (L2 reuse of qemb).
__global__ void k_attn(const float* __restrict__ qemb, const float* __restrict__ qmask_g,
                       const float* __restrict__ proto_f32,
                       u16* __restrict__ qf, u16* __restrict__ sup_ws,
                       float* __restrict__ p2m_ws, float* __restrict__ qssum_ws) {
    int x = blockIdx.x;
    int xcd = x & 7, slot = x >> 3;
    int g = (slot / 5) * 8 + xcd;           // q_idx 0..39
    int n2 = slot % 5;
    int bq = g * 5 + n2;
    int q_idx = g;
    int bn = (bq / (N_ * Q_ * N_)) * N_ + (bq % N_);
    __shared__ float s_proto[T_ * D_];
    __shared__ float s_att[T_][L_];
    __shared__ float s_ps[T_][L_];
    __shared__ float s_p2[L_][8];
    __shared__ float s_qm[L_];
    int tid = threadIdx.x;
    int w = tid >> 6, lane = tid & 63;
    for (int i = tid; i < T_ * D_; i += 256) s_proto[i] = proto_f32[bn * T_ * D_ + i];
    if (tid < L_) s_qm[tid] = qmask_g[(long)q_idx * L_ + tid];
    __syncthreads();
    for (int p = tid; p < T_ * L_; p += 256) {
        int t = p >> 7, q = p & (L_ - 1);
        const float* pp = s_proto + t * D_;
        const float4* qp = (const float4*)(qemb + ((size_t)q_idx * L_ + q) * D_);
        float acc = 0.f;
        #pragma unroll 4
        for (int d = 0; d < D_ / 4; ++d) {
            float4 v = qp[d];
            acc += v.x * pp[4 * d] + v.y * pp[4 * d + 1] + v.z * pp[4 * d + 2] + v.w * pp[4 * d + 3];
        }
        s_att[t][q] = acc + 100.f * s_qm[q];
    }
    __syncthreads();
    if (tid < T_) {                       // softmax over q (support path)
        int t = tid; float m = -1e30f;
        for (int q = 0; q < L_; ++q) m = fmaxf(m, s_att[t][q]);
        float ss = 0.f;
        for (int q = 0; q < L_; ++q) { float e = __expf(s_att[t][q] - m); s_ps[t][q] = e; ss += e; }
        float inv = 1.f / ss;
        for (int q = 0; q < L_; ++q) s_ps[t][q] *= inv;
    } else if (tid >= 128) {              // softmax over t (query path) -> masked weights
        int q = tid - 128; float m = -1e30f;
        float e[T_];
        #pragma unroll
        for (int t = 0; t < T_; ++t) m = fmaxf(m, s_att[t][q]);
        float ss = 0.f;
        #pragma unroll
        for (int t = 0; t < T_; ++t) { e[t] = __expf(s_att[t][q] - m); ss += e[t]; }
        float inv = s_qm[q] / ss;
        #pragma unroll
        for (int t = 0; t < T_; ++t) {
            s_p2[q][t] = e[t] * inv;
            p2m_ws[((size_t)bq * T_ + t) * L_ + q] = e[t] * inv;
        }
    } else if (tid == 5) {
        float s = 0.f;
        for (int q = 0; q < L_; ++q) s += s_qm[q];
        qssum_ws[bq] = s;
    }
    __syncthreads();
    u16* qfb = qf + (size_t)bq * AROWS * KFQ;
    {   // support_[t] -> sup_ws (bf16) + es rows 128..132 of qf (chunks 2,3)
        float acc[T_][3] = {};
        #pragma unroll 4
        for (int q = 0; q < L_; ++q) {
            const float* qp = qemb + ((size_t)q_idx * L_ + q) * D_;
            float qv[3];
            #pragma unroll
            for (int s = 0; s < 3; ++s) qv[s] = qp[tid + s * 256];
            #pragma unroll
            for (int t = 0; t < T_; ++t) {
                float p = s_ps[t][q];
                #pragma unroll
                for (int s = 0; s < 3; ++s) acc[t][s] += p * qv[s];
            }
        }
        #pragma unroll
        for (int t = 0; t < T_; ++t) {
            u16* er = qfb + (size_t)(128 + t) * KFQ;
            #pragma unroll
            for (int s = 0; s < 3; ++s) {
                int d = tid + s * 256;
                float p = s_proto[t * D_ + d];
                float sv = acc[t][s];
                sup_ws[((size_t)bq * T_ + t) * D_ + d] = f2bf(sv);
                er[d]       = f2bf(fabsf(p - sv));
                er[768 + d] = f2bf(p * sv);
            }
        }
    }
    // query rows 0..127: wave per row, coalesced 16B stores
    for (int rr = 0; rr < 32; ++rr) {
        int row = w * 32 + rr;
        float p0 = s_p2[row][0], p1 = s_p2[row][1], p2v = s_p2[row][2];
        float p3 = s_p2[row][3], p4 = s_p2[row][4];
        const float* qrow = qemb + ((size_t)q_idx * L_ + row) * D_;
        u16* qr = qfb + (size_t)row * KFQ;
        #pragma unroll
        for (int pass = 0; pass < 2; ++pass) {
            int u = lane + pass * 64;
            if (u < 96) {
                int d = u * 8;
                float4 a0 = *(const float4*)(qrow + d);
                float4 a1 = *(const float4*)(qrow + d + 4);
                float qv[8] = {a0.x, a0.y, a0.z, a0.w, a1.x, a1.y, a1.z, a1.w};
                short8 o2, o3;
                #pragma unroll
                for (int i = 0; i < 8; ++i) {
                    float m2 = p0 * s_proto[d + i] + p1 * s_proto[D_ + d + i]
                             + p2v * s_proto[2 * D_ + d + i] + p3 * s_proto[3 * D_ + d + i]
                             + p4 * s_proto[4 * D_ + d + i];
                    o2[i] = (short)f2bf(fabsf(qv[i] - m2));
                    o3[i] = (short)f2bf(qv[i] * m2);
                }
                *(short8*)(qr + d)       = o2;
                *(short8*)(qr + 768 + d) = o3;
            }
        }
    }
    {   // zero pad rows 133..143
        u16* pr = qfb + (size_t)133 * KFQ;
        short8 z = short8{0, 0, 0, 0, 0, 0, 0, 0};
        for (int i = tid; i < (11 * KFQ) / 8; i += 256) *(short8*)(pr + i * 8) = z;
    }
}

// ---------------- K3: G1 GEMM: [qemb(5120); proto(50); pad] @ W1(chunk0)^T -> bf16 ----------------
#define SWZ(g, r) (((g) << 4) + ((r) ^ ((g) << 2)))
__global__ __launch_bounds__(256) void k_gemm_g1(const u16* __restrict__ qemb_bf,
                                                 const u16* __restrict__ proto_bf,
                                                 const u16* __restrict__ projw_bf,
                                                 u16* __restrict__ g1) {
    int mbase = blockIdx.y * 128;
    int jbase = blockIdx.x * 128;
    __shared__ __align__(16) u16 sA[8 * 512];
    __shared__ __align__(16) u16 sB[8 * 512];
    int tid = threadIdx.x;
    int lane = tid & 63, w = tid >> 6, quad = lane >> 4, l16 = lane & 15;
    f32x4 zero = {0.f, 0.f, 0.f, 0.f};
    f32x4 acc[8][2];
    #pragma unroll
    for (int rt = 0; rt < 8; ++rt) { acc[rt][0] = zero; acc[rt][1] = zero; }

    for (int kt = 0; kt < 24; ++kt) {
        int k0 = kt * 32;
        __syncthreads();
        #pragma unroll
        for (int j = 0; j < 2; ++j) {
            int v = tid + j * 256, row = v >> 2, g = v & 3;
            *(uint4*)(sB + (((row >> 4) << 6) + SWZ(g, row & 15)) * 8) =
                *(const uint4*)(projw_bf + (size_t)(jbase + row) * K4_ + k0 + g * 8);
            int grow = mbase + row;
            uint4 av = uint4{0u, 0u, 0u, 0u};
            if (grow < 5120)      av = *(const uint4*)(qemb_bf + (size_t)grow * D_ + k0 + g * 8);
            else if (grow < 5170) av = *(const uint4*)(proto_bf + (size_t)(grow - 5120) * D_ + k0 + g * 8);
            *(uint4*)(sA + (((row >> 4) << 6) + SWZ(g, row & 15)) * 8) = av;
        }
        __syncthreads();
        short8 af[8], bfr[2];
        #pragma unroll
        for (int rt = 0; rt < 8; ++rt)
            af[rt] = *(const short8*)(sA + ((rt << 6) + SWZ(quad, l16)) * 8);
        #pragma unroll
        for (int jj = 0; jj < 2; ++jj)
            bfr[jj] = *(const short8*)(sB + (((w * 2 + jj) << 6) + SWZ(quad, l16)) * 8);
        #pragma unroll
        for (int rt = 0; rt < 8; ++rt)
            #pragma unroll
            for (int jj = 0; jj < 2; ++jj)
                acc[rt][jj] = __builtin_amdgcn_mfma_f32_16x16x32_bf16(af[rt], bfr[jj], acc[rt][jj], 0, 0, 0);
    }
    #pragma unroll
    for (int jj = 0; jj < 2; ++jj) {
        int col = jbase + (w * 2 + jj) * 16 + l16;
        #pragma unroll
        for (int rt = 0; rt < 8; ++rt)
            #pragma unroll
            for (int r = 0; r < 4; ++r) {
                int row = mbase + rt * 16 + quad * 4 + r;
                g1[(size_t)row * D_ + col] = f2bf(acc[rt][jj][r]);
            }
    }
}

// ---------------- K3b: W2 GEMM: [sup(1000); proto(50); pad] @ W2(chunk1)^T -> sw2, pw2 ----------------
__global__ __launch_bounds__(256) void k_gemm_w2(const u16* __restrict__ sup_ws,
                                                 const u16* __restrict__ proto_bf,
                                                 const u16* __restrict__ projw_bf,
                                                 u16* __restrict__ sw2, u16* __restrict__ pw2) {
    int mbase = blockIdx.y * 128;
    int jbase = blockIdx.x * 128;
    __shared__ __align__(16) u16 sA[8 * 512];
    __shared__ __align__(16) u16 sB[8 * 512];
    int tid = threadIdx.x;
    int lane = tid & 63, w = tid >> 6, quad = lane >> 4, l16 = lane & 15;
    f32x4 zero = {0.f, 0.f, 0.f, 0.f};
    f32x4 acc[8][2];
    #pragma unroll
    for (int rt = 0; rt < 8; ++rt) { acc[rt][0] = zero; acc[rt][1] = zero; }

    for (int kt = 0; kt < 24; ++kt) {
        int k0 = kt * 32;
        __syncthreads();
        #pragma unroll
        for (int j = 0; j < 2; ++j) {
            int v = tid + j * 256, row = v >> 2, g = v & 3;
            *(uint4*)(sB + (((row >> 4) << 6) + SWZ(g, row & 15)) * 8) =
                *(const uint4*)(projw_bf + (size_t)(jbase + row) * K4_ + 768 + k0 + g * 8);
            int grow = mbase + row;
            uint4 av = uint4{0u, 0u, 0u, 0u};
            if (grow < 1000)      av = *(const uint4*)(sup_ws + (size_t)grow * D_ + k0 + g * 8);
            else if (grow < 1050) av = *(const uint4*)(proto_bf + (size_t)(grow - 1000) * D_ + k0 + g * 8);
            *(uint4*)(sA + (((row >> 4) << 6) + SWZ(g, row & 15)) * 8) = av;
        }
        __syncthreads();
        short8 af[8], bfr[2];
        #pragma unroll
        for (int rt = 0; rt < 8; ++rt)
            af[rt] = *(const short8*)(sA + ((rt << 6) + SWZ(quad, l16)) * 8);
        #pragma unroll
        for (int jj = 0; jj < 2; ++jj)
            bfr[jj] = *(const short8*)(sB + (((w * 2 + jj) << 6) + SWZ(quad, l16)) * 8);
        #pragma unroll
        for (int rt = 0; rt < 8; ++rt)
            #pragma unroll
            for (int jj = 0; jj < 2; ++jj)
                acc[rt][jj] = __builtin_amdgcn_mfma_f32_16x16x32_bf16(af[rt], bfr[jj], acc[rt][jj], 0, 0, 0);
    }
    #pragma unroll
    for (int jj = 0; jj < 2; ++jj) {
        int col = jbase + (w * 2 + jj) * 16 + l16;
        #pragma unroll
        for (int rt = 0; rt < 8; ++rt)
            #pragma unroll
            for (int r = 0; r < 4; ++r) {
                int row = mbase + rt * 16 + quad * 4 + r;
                if (row < 1000)      sw2[(size_t)row * D_ + col] = f2bf(acc[rt][jj][r]);
                else if (row < 1050) pw2[(size_t)(row - 1000) * D_ + col] = f2bf(acc[rt][jj][r]);
            }
    }
}

// ---------------- K4: main GEMM (K=1536, chunks 2,3) + chunk0/1 epilogue + aggregation ----------------
// 1D grid 1200; swizzle: 6 j-blocks of a bq share an XCD (qf L2 reuse).
__global__ __launch_bounds__(256) void k_gemm_q(
        const u16* __restrict__ qf, const u16* __restrict__ projw_bf,
        const float* __restrict__ projb, const u16* __restrict__ g1,
        const u16* __restrict__ pw2, const u16* __restrict__ sw2,
        const float* __restrict__ p2m, const float* __restrict__ qssum_ws,
        u16* __restrict__ cat_ws) {
    int x = blockIdx.x;
    int xcd = x & 7, slot = x >> 3;
    int bq = (slot / 6) * 8 + xcd;
    int jbase = (slot % 6) * 128;
    int q_idx = bq / N_;
    int bn = (bq / (N_ * Q_ * N_)) * N_ + (bq % N_);
    __shared__ __align__(16) u16 sA[AROWS * 32];
    __shared__ __align__(16) u16 sB[128 * 32];
    __shared__ float s_p2mL[T_ * 128];
    __shared__ float s_pw2L[T_ * 128];
    int tid = threadIdx.x;
    int lane = tid & 63, w = tid >> 6, quad = lane >> 4, l16 = lane & 15;
    int srow = lane >> 2, sko = lane & 3;
    const u16* Ab = qf + (size_t)bq * AROWS * KFQ + (size_t)srow * KFQ + sko * 8;
    const u16* Bb = projw_bf + (size_t)jbase * K4_ + 1536 + (size_t)srow * K4_ + sko * 8;
    u16* lA0 = sA + (w * 16) * 32;
    u16* lA1 = sA + (64 + w * 16) * 32;
    u16* lA2 = sA + 128 * 32;                      // wave 0 only
    u16* lB0 = sB + (w * 16) * 32;
    u16* lB1 = sB + (64 + w * 16) * 32;

    f32x4 zero = {0.f, 0.f, 0.f, 0.f};
    f32x4 acc[9][2];
    #pragma unroll
    for (int rt = 0; rt < 9; ++rt) { acc[rt][0] = zero; acc[rt][1] = zero; }

    for (int kt = 0; kt < KFQ / 32; ++kt) {
        int k0 = kt * 32;
        __syncthreads();
        gl_lds16(Ab + (size_t)(w * 16) * KFQ + k0, lA0);
        gl_lds16(Ab + (size_t)(64 + w * 16) * KFQ + k0, lA1);
        if (w == 0) gl_lds16(Ab + (size_t)128 * KFQ + k0, lA2);
        gl_lds16(Bb + (size_t)(w * 16) * K4_ + k0, lB0);
        gl_lds16(Bb + (size_t)(64 + w * 16) * K4_ + k0, lB1);
        __syncthreads();
        short8 af[9], bfr[2];
        #pragma unroll
        for (int rt = 0; rt < 9; ++rt)
            af[rt] = *(const short8*)(sA + (rt * 16 + l16) * 32 + quad * 8);
        #pragma unroll
        for (int jj = 0; jj < 2; ++jj)
            bfr[jj] = *(const short8*)(sB + ((w * 2 + jj) * 16 + l16) * 32 + quad * 8);
        #pragma unroll
        for (int rt = 0; rt < 9; ++rt)
            #pragma unroll
            for (int jj = 0; jj < 2; ++jj)
                acc[rt][jj] = __builtin_amdgcn_mfma_f32_16x16x32_bf16(af[rt], bfr[jj], acc[rt][jj], 0, 0, 0);
    }
    // epilogue staging: p2m + pw2 slices for this (bq, j) block
    for (int i = tid; i < T_ * 128; i += 256) {
        s_p2mL[i] = p2m[(size_t)bq * (T_ * 128) + i];
        s_pw2L[i] = bf2f(pw2[(size_t)(bn * T_ + (i >> 7)) * D_ + jbase + (i & 127)]);
    }
    __syncthreads();
    float inv_qs = 1.f / qssum_ws[bq];
    #pragma unroll
    for (int jj = 0; jj < 2; ++jj) {
        int col = jbase + (w * 2 + jj) * 16 + l16;
        int cj = (w * 2 + jj) * 16 + l16;
        float bias = projb[col];
        float qmax = 0.f, qsum = 0.f, smax = 0.f, ssum = 0.f;
        #pragma unroll
        for (int rt = 0; rt < 8; ++rt) {
            #pragma unroll
            for (int r = 0; r < 4; ++r) {
                int row = rt * 16 + quad * 4 + r;
                float g1v = bf2f(g1[(size_t)(q_idx * 128 + row) * D_ + col]);
                float mix = s_p2mL[row] * s_pw2L[cj]
                          + s_p2mL[128 + row] * s_pw2L[128 + cj]
                          + s_p2mL[256 + row] * s_pw2L[256 + cj]
                          + s_p2mL[384 + row] * s_pw2L[384 + cj]
                          + s_p2mL[512 + row] * s_pw2L[512 + cj];
                float v = fmaxf(acc[rt][jj][r] + g1v + mix + bias, 0.f);
                qmax = fmaxf(qmax, v); qsum += v;
            }
        }
        #pragma unroll
        for (int r = 0; r < 4; ++r) {
            int t = quad * 4 + r;
            if (t < T_) {
                float g1v = bf2f(g1[(size_t)(5120 + bn * T_ + t) * D_ + col]);
                float s2v = bf2f(sw2[(size_t)(bq * T_ + t) * D_ + col]);
                float v = fmaxf(acc[8][jj][r] + g1v + s2v + bias, 0.f);
                smax = fmaxf(smax, v); ssum += v;
            }
        }
        qmax = fmaxf(qmax, __shfl_xor(qmax, 16, 64)); qmax = fmaxf(qmax, __shfl_xor(qmax, 32, 64));
        qsum += __shfl_xor(qsum, 16, 64);             qsum += __shfl_xor(qsum, 32, 64);
        smax = fmaxf(smax, __shfl_xor(smax, 16, 64)); smax = fmaxf(smax, __shfl_xor(smax, 32, 64));
        ssum += __shfl_xor(ssum, 16, 64);             ssum += __shfl_xor(ssum, 32, 64);
        if (quad == 0) {
            u16* cp = cat_ws + (size_t)bq * K4_;
            cp[col]           = f2bf(qmax);
            cp[D_ + col]      = f2bf(qsum * inv_qs);
            cp[2 * D_ + col]  = f2bf(smax);
            cp[3 * D_ + col]  = f2bf(ssum * 0.2f);
        }
    }
}

// ---------------- K5: relation MLP GEMM, split-K -> f32 partials ----------------
#define AST  40
__global__ __launch_bounds__(256) void k_relmlp(const u16* __restrict__ cat_ws,
                                                const u16* __restrict__ w1,
                                                float* __restrict__ part) {
    int mbase = blockIdx.y * 64;
    int jbase = blockIdx.x * 128;
    int ks = blockIdx.z;
    __shared__ __align__(16) u16 sA[64 * AST];
    __shared__ __align__(16) u16 sB[128 * AST];
    int tid = threadIdx.x;
    int lane = tid & 63, w = tid >> 6, quad = lane >> 4, l16 = lane & 15;
    f32x4 zero = {0.f, 0.f, 0.f, 0.f};
    f32x4 acc[4][2];
    #pragma unroll
    for (int rt = 0; rt < 4; ++rt) { acc[rt][0] = zero; acc[rt][1] = zero; }

    for (int kt = ks * 12; kt < ks * 12 + 12; ++kt) {
        int k0 = kt * 32;
        __syncthreads();
        {
            int row = tid >> 2, ko = (tid & 3) * 8;
            int grow = mbase + row;
            short8 val = short8{0, 0, 0, 0, 0, 0, 0, 0};
            if (grow < BQ_) val = *(const short8*)(cat_ws + (size_t)grow * K4_ + k0 + ko);
            *(short8*)(sA + row * AST + ko) = val;
        }
        for (int u = tid; u < 512; u += 256) {
            int row = u >> 2, ko = (u & 3) * 8;
            *(short8*)(sB + row * AST + ko) =
                *(const short8*)(w1 + (size_t)(jbase + row) * K4_ + k0 + ko);
        }
        __syncthreads();
        short8 af[4], bfr[2];
        #pragma unroll
        for (int rt = 0; rt < 4; ++rt)
            af[rt] = *(const short8*)(sA + (rt * 16 + l16) * AST + quad * 8);
        #pragma unroll
        for (int jj = 0; jj < 2; ++jj)
            bfr[jj] = *(const short8*)(sB + ((2 * w + jj) * 16 + l16) * AST + quad * 8);
        #pragma unroll
        for (int rt = 0; rt < 4; ++rt)
            #pragma unroll
            for (int jj = 0; jj < 2; ++jj)
                acc[rt][jj] = __builtin_amdgcn_mfma_f32_16x16x32_bf16(af[rt], bfr[jj], acc[rt][jj], 0, 0, 0);
    }
    #pragma unroll
    for (int jj = 0; jj < 2; ++jj) {
        int col = jbase + (2 * w + jj) * 16 + l16;
        #pragma unroll
        for (int rt = 0; rt < 4; ++rt) {
            #pragma unroll
            for (int r = 0; r < 4; ++r) {
                int grow = mbase + rt * 16 + quad * 4 + r;
                if (grow < BQ_)
                    part[((size_t)ks * BQ_ + grow) * D_ + col] = acc[rt][jj][r];
            }
        }
    }
}

// ---------------- K6: finish — sum partials, bias+relu, dot w2 ----------------
__global__ void k_rel_fin(const float* __restrict__ part, const float* __restrict__ b1,
                          const float* __restrict__ w2, const float* __restrict__ b2,
                          float* __restrict__ out) {
    int bq = blockIdx.x, tid = threadIdx.x;
    float a = 0.f;
    #pragma unroll
    for (int s = 0; s < 3; ++s) {
        int col = tid + s * 256;
        float sum = 0.f;
        #pragma unroll
        for (int ks = 0; ks < 8; ++ks) sum += part[((size_t)ks * BQ_ + bq) * D_ + col];
        float h = fmaxf(sum + b1[col], 0.f);
        a += h * w2[col];
    }
    __shared__ float red[256];
    red[tid] = a; __syncthreads();
    for (int off = 128; off >= 1; off >>= 1) {
        if (tid < off) red[tid] += red[tid + off];
        __syncthreads();
    }
    if (tid == 0) out[bq] = red[0] + b2[0];
}

extern "C" void kernel_launch(void* const* d_in, const int* in_sizes, int n_in,
                              void* d_out, int out_size, void* d_ws, size_t ws_size,
                              hipStream_t stream) {
    (void)in_sizes; (void)n_in; (void)out_size; (void)ws_size;
    const float* semb  = (const float*)d_in[0];
    const float* qemb  = (const float*)d_in[1];
    const float* smask = (const float*)d_in[2];
    const float* qmask = (const float*)d_in[3];
    const float* label = (const float*)d_in[4];
    const float* projw = (const float*)d_in[5];
    const float* projb = (const float*)d_in[6];
    const float* relw1 = (const float*)d_in[7];
    const float* relb1 = (const float*)d_in[8];
    const float* relw2 = (const float*)d_in[9];
    const float* relb2 = (const float*)d_in[10];

    char* ws = (char*)d_ws;
    u16*   qemb_bf   = (u16*)  (ws + 0);           // 7,864,320
    u16*   projw_bf  = (u16*)  (ws + 7864320);     // 4,718,592
    u16*   relw1_bf  = (u16*)  (ws + 12582912);    // 4,718,592
    float* proto_shot= (float*)(ws + 17301504);    // 768,000
    float* proto_f32 = (float*)(ws + 18069504);    // 153,600
    u16*   proto_bf  = (u16*)  (ws + 18223104);    // 76,800
    float* qssum     = (float*)(ws + 18299904);    // 896
    u16*   sup_ws    = (u16*)  (ws + 18300800);    // 1,536,000
    float* p2m_ws    = (float*)(ws + 19836800);    // 512,000
    u16*   pw2_ws    = (u16*)  (ws + 20348800);    // 76,800
    u16*   sw2_ws    = (u16*)  (ws + 20425600);    // 1,536,000
    u16*   cat_ws    = (u16*)  (ws + 21961600);    // 1,228,800
    u16*   g1_ws     = (u16*)  (ws + 23190400);    // 8,060,928
    float* part_ws   = (float*)(ws + 31251328);    // 4,915,200
    u16*   qf_ws     = (u16*)  (ws + 36166528);    // 200*144*1536*2 = 88,473,600
    // total 124,640,128 bytes (~124.6 MB; round-7's 160.3 MB fit, so this fits)

    k_convert3<<<2048, 256, 0, stream>>>(qemb, projw, relw1, qemb_bf, projw_bf, relw1_bf);
    k_proto_shot<<<BNK_, 256, 0, stream>>>(label, smask, semb, proto_shot);
    k_proto_mean<<<150, 256, 0, stream>>>(proto_shot, proto_f32, proto_bf);
    k_attn<<<BQ_, 256, 0, stream>>>(qemb, qmask, proto_f32, qf_ws, sup_ws, p2m_ws, qssum);
    k_gemm_g1<<<dim3(6, 41), 256, 0, stream>>>(qemb_bf, proto_bf, projw_bf, g1_ws);
    k_gemm_w2<<<dim3(6, 9), 256, 0, stream>>>(sup_ws, proto_bf, projw_bf, sw2_ws, pw2_ws);
    k_gemm_q<<<1200, 256, 0, stream>>>(qf_ws, projw_bf, projb, g1_ws, pw2_ws, sw2_ws,
                                       p2m_ws, qssum, cat_ws);
    k_relmlp<<<dim3(6, 4, 8), 256, 0, stream>>>(cat_ws, relw1_bf, part_ws);
    k_rel_fin<<<BQ_, 256, 0, stream>>>(part_ws, relb1, relw2, relb2, (float*)d_out);
}

// Round 9
// 531.699 us; speedup vs baseline: 1.3208x; 1.0093x over previous
//
#include <hip/hip_runtime.h>

typedef unsigned short u16;
typedef __attribute__((ext_vector_type(8))) short short8;
typedef __attribute__((ext_vector_type(4))) float f32x4;

#define B_   2
#define N_   5
#define K_   5
#define Q_   4
#define T_   5
#define D_   768
#define L_   128
#define BN_  (B_*N_)            // 10
#define BNK_ (B_*N_*K_)         // 50
#define BQ_  (B_*N_*Q_*N_)      // 200
#define K4_  (4*D_)             // 3072
#define KFQ  1536               // fuse K in main GEMM (chunks 2,3 only)
#define AROWS 144               // 128 query + 5 es + 11 pad

#define QEMB_N  (40*128*768)    // 3,932,160
#define PROJW_N (768*3072)      // 2,359,296

__device__ __forceinline__ float bf2f(u16 u) {
    return __uint_as_float(((unsigned)u) << 16);
}
__device__ __forceinline__ u16 f2bf(float f) {
    unsigned u = __float_as_uint(f);
    return (u16)((u + 0x7fffu + ((u >> 16) & 1u)) >> 16);
}
// async global->LDS, 16B per lane; lds base wave-uniform (HW adds lane*16)
__device__ __forceinline__ void gl_lds16(const u16* g, u16* l) {
    __builtin_amdgcn_global_load_lds(
        (const __attribute__((address_space(1))) unsigned int*)g,
        (__attribute__((address_space(3))) unsigned int*)l, 16, 0, 0);
}

// ---------------- K0: convert qemb/projw/relw1 f32 -> bf16 ----------------
__global__ void k_convert3(const float* __restrict__ q, const float* __restrict__ pw,
                           const float* __restrict__ rw, u16* __restrict__ qo,
                           u16* __restrict__ po, u16* __restrict__ ro) {
    const long n1 = QEMB_N / 4, n2 = PROJW_N / 4;
    const long total = n1 + 2 * n2;
    for (long i = (long)blockIdx.x * 256 + threadIdx.x; i < total; i += (long)gridDim.x * 256) {
        const float* src; u16* dst; long k;
        if (i < n1)            { src = q;  dst = qo; k = i; }
        else if (i < n1 + n2)  { src = pw; dst = po; k = i - n1; }
        else                   { src = rw; dst = ro; k = i - n1 - n2; }
        float4 v = ((const float4*)src)[k];
        u16 o[4] = {f2bf(v.x), f2bf(v.y), f2bf(v.z), f2bf(v.w)};
        *(uint2*)(dst + k * 4) = *(const uint2*)o;
    }
}

// ---------------- K1: per-shot tag prototypes ----------------
__global__ void k_proto_shot(const float* __restrict__ label, const float* __restrict__ smask,
                             const float* __restrict__ semb, float* __restrict__ proto_shot) {
    int bnk = blockIdx.x;
    __shared__ int   s_tag[L_];
    __shared__ float s_w[L_];
    __shared__ float s_cnt[T_];
    int tid = threadIdx.x;
    if (tid < L_) {
        const float* lp = label + ((long)bnk * L_ + tid) * T_;
        float best = lp[0]; int bi = 0;
        #pragma unroll
        for (int t = 1; t < T_; ++t) { float v = lp[t]; if (v > best) { best = v; bi = t; } }
        s_tag[tid] = bi;
        s_w[tid]   = (bi == 0) ? smask[(long)bnk * L_ + tid] : 1.0f;
    }
    __syncthreads();
    if (tid < T_) {
        float c = 0.f;
        for (int l = 0; l < L_; ++l) if (s_tag[l] == tid) c += s_w[l];
        s_cnt[tid] = c;
    }
    __syncthreads();
    float acc[3][T_] = {};
    for (int l = 0; l < L_; ++l) {
        float w = s_w[l]; int tg = s_tag[l];
        const float* ep = semb + ((long)bnk * L_ + l) * D_;
        #pragma unroll
        for (int s = 0; s < 3; ++s) {
            float e = ep[tid + s * 256] * w;
            #pragma unroll
            for (int t = 0; t < T_; ++t) acc[s][t] += (tg == t) ? e : 0.0f;
        }
    }
    #pragma unroll
    for (int s = 0; s < 3; ++s) {
        int d = tid + s * 256;
        #pragma unroll
        for (int t = 0; t < T_; ++t) {
            float c = s_cnt[t];
            float v = (c > 0.f) ? acc[s][t] / fmaxf(c, 1.f) : 0.f;
            proto_shot[(bnk * T_ + t) * D_ + d] = v;
        }
    }
}

// ---------------- K1b: mean over K shots ----------------
__global__ void k_proto_mean(const float* __restrict__ proto_shot,
                             float* __restrict__ proto_f32, u16* __restrict__ proto_bf) {
    int idx = blockIdx.x * 256 + threadIdx.x;
    if (idx >= BN_ * T_ * D_) return;
    int bn = idx / (T_ * D_);
    int rem = idx - bn * (T_ * D_);
    float s = 0.f;
    #pragma unroll
    for (int k = 0; k < K_; ++k) s += proto_shot[(bn * K_ + k) * (T_ * D_) + rem];
    s *= (1.f / K_);
    proto_f32[idx] = s;
    proto_bf[idx]  = f2bf(s);
}

// ---------------- K2: co-attention -> qf (chunks 2,3), sup, p2m, qssum ----------------
__global__ void k_attn(const float* __restrict__ qemb, const float* __restrict__ qmask_g,
                       const float* __restrict__ proto_f32,
                       u16* __restrict__ qf, u16* __restrict__ sup_ws,
                       float* __restrict__ p2m_ws, float* __restrict__ qssum_ws) {
    int x = blockIdx.x;
    int xcd = x & 7, slot = x >> 3;
    int g = (slot / 5) * 8 + xcd;           // q_idx 0..39
    int n2 = slot % 5;
    int bq = g * 5 + n2;
    int q_idx = g;
    int bn = (bq / (N_ * Q_ * N_)) * N_ + (bq % N_);
    __shared__ float s_proto[T_ * D_];
    __shared__ float s_att[T_][L_];
    __shared__ float s_ps[T_][L_];
    __shared__ float s_p2[L_][8];
    __shared__ float s_qm[L_];
    int tid = threadIdx.x;
    int w = tid >> 6, lane = tid & 63;
    for (int i = tid; i < T_ * D_; i += 256) s_proto[i] = proto_f32[bn * T_ * D_ + i];
    if (tid < L_) s_qm[tid] = qmask_g[(long)q_idx * L_ + tid];
    __syncthreads();
    for (int p = tid; p < T_ * L_; p += 256) {
        int t = p >> 7, q = p & (L_ - 1);
        const float* pp = s_proto + t * D_;
        const float4* qp = (const float4*)(qemb + ((size_t)q_idx * L_ + q) * D_);
        float acc = 0.f;
        #pragma unroll 4
        for (int d = 0; d < D_ / 4; ++d) {
            float4 v = qp[d];
            acc += v.x * pp[4 * d] + v.y * pp[4 * d + 1] + v.z * pp[4 * d + 2] + v.w * pp[4 * d + 3];
        }
        s_att[t][q] = acc + 100.f * s_qm[q];
    }
    __syncthreads();
    if (tid < T_) {                       // softmax over q (support path)
        int t = tid; float m = -1e30f;
        for (int q = 0; q < L_; ++q) m = fmaxf(m, s_att[t][q]);
        float ss = 0.f;
        for (int q = 0; q < L_; ++q) { float e = __expf(s_att[t][q] - m); s_ps[t][q] = e; ss += e; }
        float inv = 1.f / ss;
        for (int q = 0; q < L_; ++q) s_ps[t][q] *= inv;
    } else if (tid >= 128) {              // softmax over t (query path) -> masked weights
        int q = tid - 128; float m = -1e30f;
        float e[T_];
        #pragma unroll
        for (int t = 0; t < T_; ++t) m = fmaxf(m, s_att[t][q]);
        float ss = 0.f;
        #pragma unroll
        for (int t = 0; t < T_; ++t) { e[t] = __expf(s_att[t][q] - m); ss += e[t]; }
        float inv = s_qm[q] / ss;
        #pragma unroll
        for (int t = 0; t < T_; ++t) {
            s_p2[q][t] = e[t] * inv;
            p2m_ws[((size_t)bq * T_ + t) * L_ + q] = e[t] * inv;
        }
    } else if (tid == 5) {
        float s = 0.f;
        for (int q = 0; q < L_; ++q) s += s_qm[q];
        qssum_ws[bq] = s;
    }
    __syncthreads();
    u16* qfb = qf + (size_t)bq * AROWS * KFQ;
    {   // support_[t] -> sup_ws (bf16) + es rows 128..132 of qf (chunks 2,3)
        float acc[T_][3] = {};
        #pragma unroll 4
        for (int q = 0; q < L_; ++q) {
            const float* qp = qemb + ((size_t)q_idx * L_ + q) * D_;
            float qv[3];
            #pragma unroll
            for (int s = 0; s < 3; ++s) qv[s] = qp[tid + s * 256];
            #pragma unroll
            for (int t = 0; t < T_; ++t) {
                float p = s_ps[t][q];
                #pragma unroll
                for (int s = 0; s < 3; ++s) acc[t][s] += p * qv[s];
            }
        }
        #pragma unroll
        for (int t = 0; t < T_; ++t) {
            u16* er = qfb + (size_t)(128 + t) * KFQ;
            #pragma unroll
            for (int s = 0; s < 3; ++s) {
                int d = tid + s * 256;
                float p = s_proto[t * D_ + d];
                float sv = acc[t][s];
                sup_ws[((size_t)bq * T_ + t) * D_ + d] = f2bf(sv);
                er[d]       = f2bf(fabsf(p - sv));
                er[768 + d] = f2bf(p * sv);
            }
        }
    }
    // query rows 0..127: wave per row, coalesced 16B stores
    for (int rr = 0; rr < 32; ++rr) {
        int row = w * 32 + rr;
        float p0 = s_p2[row][0], p1 = s_p2[row][1], p2v = s_p2[row][2];
        float p3 = s_p2[row][3], p4 = s_p2[row][4];
        const float* qrow = qemb + ((size_t)q_idx * L_ + row) * D_;
        u16* qr = qfb + (size_t)row * KFQ;
        #pragma unroll
        for (int pass = 0; pass < 2; ++pass) {
            int u = lane + pass * 64;
            if (u < 96) {
                int d = u * 8;
                float4 a0 = *(const float4*)(qrow + d);
                float4 a1 = *(const float4*)(qrow + d + 4);
                float qv[8] = {a0.x, a0.y, a0.z, a0.w, a1.x, a1.y, a1.z, a1.w};
                short8 o2, o3;
                #pragma unroll
                for (int i = 0; i < 8; ++i) {
                    float m2 = p0 * s_proto[d + i] + p1 * s_proto[D_ + d + i]
                             + p2v * s_proto[2 * D_ + d + i] + p3 * s_proto[3 * D_ + d + i]
                             + p4 * s_proto[4 * D_ + d + i];
                    o2[i] = (short)f2bf(fabsf(qv[i] - m2));
                    o3[i] = (short)f2bf(qv[i] * m2);
                }
                *(short8*)(qr + d)       = o2;
                *(short8*)(qr + 768 + d) = o3;
            }
        }
    }
    {   // zero pad rows 133..143
        u16* pr = qfb + (size_t)133 * KFQ;
        short8 z = short8{0, 0, 0, 0, 0, 0, 0, 0};
        for (int i = tid; i < (11 * KFQ) / 8; i += 256) *(short8*)(pr + i * 8) = z;
    }
}

// ---------------- K3: G1 GEMM: [qemb(5120); proto(50); pad] @ W1(chunk0)^T -> bf16 ----------------
#define SWZ(g, r) (((g) << 4) + ((r) ^ ((g) << 2)))
__global__ __launch_bounds__(256) void k_gemm_g1(const u16* __restrict__ qemb_bf,
                                                 const u16* __restrict__ proto_bf,
                                                 const u16* __restrict__ projw_bf,
                                                 u16* __restrict__ g1) {
    int mbase = blockIdx.y * 128;
    int jbase = blockIdx.x * 128;
    __shared__ __align__(16) u16 sA[8 * 512];
    __shared__ __align__(16) u16 sB[8 * 512];
    int tid = threadIdx.x;
    int lane = tid & 63, w = tid >> 6, quad = lane >> 4, l16 = lane & 15;
    f32x4 zero = {0.f, 0.f, 0.f, 0.f};
    f32x4 acc[8][2];
    #pragma unroll
    for (int rt = 0; rt < 8; ++rt) { acc[rt][0] = zero; acc[rt][1] = zero; }

    for (int kt = 0; kt < 24; ++kt) {
        int k0 = kt * 32;
        __syncthreads();
        #pragma unroll
        for (int j = 0; j < 2; ++j) {
            int v = tid + j * 256, row = v >> 2, g = v & 3;
            *(uint4*)(sB + (((row >> 4) << 6) + SWZ(g, row & 15)) * 8) =
                *(const uint4*)(projw_bf + (size_t)(jbase + row) * K4_ + k0 + g * 8);
            int grow = mbase + row;
            uint4 av = uint4{0u, 0u, 0u, 0u};
            if (grow < 5120)      av = *(const uint4*)(qemb_bf + (size_t)grow * D_ + k0 + g * 8);
            else if (grow < 5170) av = *(const uint4*)(proto_bf + (size_t)(grow - 5120) * D_ + k0 + g * 8);
            *(uint4*)(sA + (((row >> 4) << 6) + SWZ(g, row & 15)) * 8) = av;
        }
        __syncthreads();
        short8 af[8], bfr[2];
        #pragma unroll
        for (int rt = 0; rt < 8; ++rt)
            af[rt] = *(const short8*)(sA + ((rt << 6) + SWZ(quad, l16)) * 8);
        #pragma unroll
        for (int jj = 0; jj < 2; ++jj)
            bfr[jj] = *(const short8*)(sB + (((w * 2 + jj) << 6) + SWZ(quad, l16)) * 8);
        #pragma unroll
        for (int rt = 0; rt < 8; ++rt)
            #pragma unroll
            for (int jj = 0; jj < 2; ++jj)
                acc[rt][jj] = __builtin_amdgcn_mfma_f32_16x16x32_bf16(af[rt], bfr[jj], acc[rt][jj], 0, 0, 0);
    }
    #pragma unroll
    for (int jj = 0; jj < 2; ++jj) {
        int col = jbase + (w * 2 + jj) * 16 + l16;
        #pragma unroll
        for (int rt = 0; rt < 8; ++rt)
            #pragma unroll
            for (int r = 0; r < 4; ++r) {
                int row = mbase + rt * 16 + quad * 4 + r;
                g1[(size_t)row * D_ + col] = f2bf(acc[rt][jj][r]);
            }
    }
}

// ---------------- K3b: W2 GEMM: [sup(1000); proto(50); pad] @ W2(chunk1)^T -> sw2, pw2 ----------------
__global__ __launch_bounds__(256) void k_gemm_w2(const u16* __restrict__ sup_ws,
                                                 const u16* __restrict__ proto_bf,
                                                 const u16* __restrict__ projw_bf,
                                                 u16* __restrict__ sw2, u16* __restrict__ pw2) {
    int mbase = blockIdx.y * 128;
    int jbase = blockIdx.x * 128;
    __shared__ __align__(16) u16 sA[8 * 512];
    __shared__ __align__(16) u16 sB[8 * 512];
    int tid = threadIdx.x;
    int lane = tid & 63, w = tid >> 6, quad = lane >> 4, l16 = lane & 15;
    f32x4 zero = {0.f, 0.f, 0.f, 0.f};
    f32x4 acc[8][2];
    #pragma unroll
    for (int rt = 0; rt < 8; ++rt) { acc[rt][0] = zero; acc[rt][1] = zero; }

    for (int kt = 0; kt < 24; ++kt) {
        int k0 = kt * 32;
        __syncthreads();
        #pragma unroll
        for (int j = 0; j < 2; ++j) {
            int v = tid + j * 256, row = v >> 2, g = v & 3;
            *(uint4*)(sB + (((row >> 4) << 6) + SWZ(g, row & 15)) * 8) =
                *(const uint4*)(projw_bf + (size_t)(jbase + row) * K4_ + 768 + k0 + g * 8);
            int grow = mbase + row;
            uint4 av = uint4{0u, 0u, 0u, 0u};
            if (grow < 1000)      av = *(const uint4*)(sup_ws + (size_t)grow * D_ + k0 + g * 8);
            else if (grow < 1050) av = *(const uint4*)(proto_bf + (size_t)(grow - 1000) * D_ + k0 + g * 8);
            *(uint4*)(sA + (((row >> 4) << 6) + SWZ(g, row & 15)) * 8) = av;
        }
        __syncthreads();
        short8 af[8], bfr[2];
        #pragma unroll
        for (int rt = 0; rt < 8; ++rt)
            af[rt] = *(const short8*)(sA + ((rt << 6) + SWZ(quad, l16)) * 8);
        #pragma unroll
        for (int jj = 0; jj < 2; ++jj)
            bfr[jj] = *(const short8*)(sB + (((w * 2 + jj) << 6) + SWZ(quad, l16)) * 8);
        #pragma unroll
        for (int rt = 0; rt < 8; ++rt)
            #pragma unroll
            for (int jj = 0; jj < 2; ++jj)
                acc[rt][jj] = __builtin_amdgcn_mfma_f32_16x16x32_bf16(af[rt], bfr[jj], acc[rt][jj], 0, 0, 0);
    }
    #pragma unroll
    for (int jj = 0; jj < 2; ++jj) {
        int col = jbase + (w * 2 + jj) * 16 + l16;
        #pragma unroll
        for (int rt = 0; rt < 8; ++rt)
            #pragma unroll
            for (int r = 0; r < 4; ++r) {
                int row = mbase + rt * 16 + quad * 4 + r;
                if (row < 1000)      sw2[(size_t)row * D_ + col] = f2bf(acc[rt][jj][r]);
                else if (row < 1050) pw2[(size_t)(row - 1000) * D_ + col] = f2bf(acc[rt][jj][r]);
            }
    }
}

// ---------------- K4: main GEMM — double-buffered LDS, 1 barrier/iter ----------------
// grid 1200 swizzled; per iter: issue next tile's global_load_lds into the other buffer
// right after the barrier, so the loads overlap this tile's MFMA phase.
__global__ __launch_bounds__(256) void k_gemm_q(
        const u16* __restrict__ qf, const u16* __restrict__ projw_bf,
        const float* __restrict__ projb, const u16* __restrict__ g1,
        const u16* __restrict__ pw2, const u16* __restrict__ sw2,
        const float* __restrict__ p2m, const float* __restrict__ qssum_ws,
        u16* __restrict__ cat_ws) {
    int x = blockIdx.x;
    int xcd = x & 7, slot = x >> 3;
    int bq = (slot / 6) * 8 + xcd;
    int jbase = (slot % 6) * 128;
    int q_idx = bq / N_;
    int bn = (bq / (N_ * Q_ * N_)) * N_ + (bq % N_);
    __shared__ __align__(16) u16 sT[2][(AROWS + 128) * 32];   // [buf][A(144)|B(128) x 32]
    __shared__ float s_p2mL[T_ * 128];
    __shared__ float s_pw2L[T_ * 128];
    int tid = threadIdx.x;
    int lane = tid & 63, w = tid >> 6, quad = lane >> 4, l16 = lane & 15;
    int srow = lane >> 2, sko = lane & 3;
    const u16* Ab = qf + ((size_t)bq * AROWS + srow) * KFQ + sko * 8;
    const u16* Bb = projw_bf + (size_t)(jbase + srow) * K4_ + 1536 + sko * 8;

    f32x4 zero = {0.f, 0.f, 0.f, 0.f};
    f32x4 acc[9][2];
    #pragma unroll
    for (int rt = 0; rt < 9; ++rt) { acc[rt][0] = zero; acc[rt][1] = zero; }

    // issue loads for k-tile kt into buffer b
    auto issue = [&](int kt, int b) {
        int k0 = kt * 32;
        u16* base = sT[b];
        gl_lds16(Ab + (size_t)(w * 16) * KFQ + k0, base + (w * 16) * 32);
        gl_lds16(Ab + (size_t)(64 + w * 16) * KFQ + k0, base + (64 + w * 16) * 32);
        if (w == 0) gl_lds16(Ab + (size_t)128 * KFQ + k0, base + 128 * 32);
        gl_lds16(Bb + (size_t)(w * 16) * K4_ + k0, base + (AROWS + w * 16) * 32);
        gl_lds16(Bb + (size_t)(64 + w * 16) * K4_ + k0, base + (AROWS + 64 + w * 16) * 32);
    };

    issue(0, 0);
    for (int kt = 0; kt < KFQ / 32; ++kt) {
        int cur = kt & 1;
        __syncthreads();                    // waits vmcnt(0): buf[cur] loads landed (overlapped w/ prev MFMA)
        if (kt + 1 < KFQ / 32) issue(kt + 1, 1 - cur);
        const u16* base = sT[cur];
        short8 af[9], bfr[2];
        #pragma unroll
        for (int rt = 0; rt < 9; ++rt)
            af[rt] = *(const short8*)(base + (rt * 16 + l16) * 32 + quad * 8);
        #pragma unroll
        for (int jj = 0; jj < 2; ++jj)
            bfr[jj] = *(const short8*)(base + (AROWS + (w * 2 + jj) * 16 + l16) * 32 + quad * 8);
        #pragma unroll
        for (int rt = 0; rt < 9; ++rt)
            #pragma unroll
            for (int jj = 0; jj < 2; ++jj)
                acc[rt][jj] = __builtin_amdgcn_mfma_f32_16x16x32_bf16(af[rt], bfr[jj], acc[rt][jj], 0, 0, 0);
    }
    // epilogue staging: p2m + pw2 slices for this (bq, j) block
    for (int i = tid; i < T_ * 128; i += 256) {
        s_p2mL[i] = p2m[(size_t)bq * (T_ * 128) + i];
        s_pw2L[i] = bf2f(pw2[(size_t)(bn * T_ + (i >> 7)) * D_ + jbase + (i & 127)]);
    }
    __syncthreads();
    float inv_qs = 1.f / qssum_ws[bq];
    #pragma unroll
    for (int jj = 0; jj < 2; ++jj) {
        int col = jbase + (w * 2 + jj) * 16 + l16;
        int cj = (w * 2 + jj) * 16 + l16;
        float bias = projb[col];
        float qmax = 0.f, qsum = 0.f, smax = 0.f, ssum = 0.f;
        #pragma unroll
        for (int rt = 0; rt < 8; ++rt) {
            #pragma unroll
            for (int r = 0; r < 4; ++r) {
                int row = rt * 16 + quad * 4 + r;
                float g1v = bf2f(g1[(size_t)(q_idx * 128 + row) * D_ + col]);
                float mix = s_p2mL[row] * s_pw2L[cj]
                          + s_p2mL[128 + row] * s_pw2L[128 + cj]
                          + s_p2mL[256 + row] * s_pw2L[256 + cj]
                          + s_p2mL[384 + row] * s_pw2L[384 + cj]
                          + s_p2mL[512 + row] * s_pw2L[512 + cj];
                float v = fmaxf(acc[rt][jj][r] + g1v + mix + bias, 0.f);
                qmax = fmaxf(qmax, v); qsum += v;
            }
        }
        #pragma unroll
        for (int r = 0; r < 4; ++r) {
            int t = quad * 4 + r;
            if (t < T_) {
                float g1v = bf2f(g1[(size_t)(5120 + bn * T_ + t) * D_ + col]);
                float s2v = bf2f(sw2[(size_t)(bq * T_ + t) * D_ + col]);
                float v = fmaxf(acc[8][jj][r] + g1v + s2v + bias, 0.f);
                smax = fmaxf(smax, v); ssum += v;
            }
        }
        qmax = fmaxf(qmax, __shfl_xor(qmax, 16, 64)); qmax = fmaxf(qmax, __shfl_xor(qmax, 32, 64));
        qsum += __shfl_xor(qsum, 16, 64);             qsum += __shfl_xor(qsum, 32, 64);
        smax = fmaxf(smax, __shfl_xor(smax, 16, 64)); smax = fmaxf(smax, __shfl_xor(smax, 32, 64));
        ssum += __shfl_xor(ssum, 16, 64);             ssum += __shfl_xor(ssum, 32, 64);
        if (quad == 0) {
            u16* cp = cat_ws + (size_t)bq * K4_;
            cp[col]           = f2bf(qmax);
            cp[D_ + col]      = f2bf(qsum * inv_qs);
            cp[2 * D_ + col]  = f2bf(smax);
            cp[3 * D_ + col]  = f2bf(ssum * 0.2f);
        }
    }
}

// ---------------- K5: relation MLP GEMM, split-K -> f32 partials ----------------
#define AST  40
__global__ __launch_bounds__(256) void k_relmlp(const u16* __restrict__ cat_ws,
                                                const u16* __restrict__ w1,
                                                float* __restrict__ part) {
    int mbase = blockIdx.y * 64;
    int jbase = blockIdx.x * 128;
    int ks = blockIdx.z;
    __shared__ __align__(16) u16 sA[64 * AST];
    __shared__ __align__(16) u16 sB[128 * AST];
    int tid = threadIdx.x;
    int lane = tid & 63, w = tid >> 6, quad = lane >> 4, l16 = lane & 15;
    f32x4 zero = {0.f, 0.f, 0.f, 0.f};
    f32x4 acc[4][2];
    #pragma unroll
    for (int rt = 0; rt < 4; ++rt) { acc[rt][0] = zero; acc[rt][1] = zero; }

    for (int kt = ks * 12; kt < ks * 12 + 12; ++kt) {
        int k0 = kt * 32;
        __syncthreads();
        {
            int row = tid >> 2, ko = (tid & 3) * 8;
            int grow = mbase + row;
            short8 val = short8{0, 0, 0, 0, 0, 0, 0, 0};
            if (grow < BQ_) val = *(const short8*)(cat_ws + (size_t)grow * K4_ + k0 + ko);
            *(short8*)(sA + row * AST + ko) = val;
        }
        for (int u = tid; u < 512; u += 256) {
            int row = u >> 2, ko = (u & 3) * 8;
            *(short8*)(sB + row * AST + ko) =
                *(const short8*)(w1 + (size_t)(jbase + row) * K4_ + k0 + ko);
        }
        __syncthreads();
        short8 af[4], bfr[2];
        #pragma unroll
        for (int rt = 0; rt < 4; ++rt)
            af[rt] = *(const short8*)(sA + (rt * 16 + l16) * AST + quad * 8);
        #pragma unroll
        for (int jj = 0; jj < 2; ++jj)
            bfr[jj] = *(const short8*)(sB + ((2 * w + jj) * 16 + l16) * AST + quad * 8);
        #pragma unroll
        for (int rt = 0; rt < 4; ++rt)
            #pragma unroll
            for (int jj = 0; jj < 2; ++jj)
                acc[rt][jj] = __builtin_amdgcn_mfma_f32_16x16x32_bf16(af[rt], bfr[jj], acc[rt][jj], 0, 0, 0);
    }
    #pragma unroll
    for (int jj = 0; jj < 2; ++jj) {
        int col = jbase + (2 * w + jj) * 16 + l16;
        #pragma unroll
        for (int rt = 0; rt < 4; ++rt) {
            #pragma unroll
            for (int r = 0; r < 4; ++r) {
                int grow = mbase + rt * 16 + quad * 4 + r;
                if (grow < BQ_)
                    part[((size_t)ks * BQ_ + grow) * D_ + col] = acc[rt][jj][r];
            }
        }
    }
}

// ---------------- K6: finish — sum partials, bias+relu, dot w2 ----------------
__global__ void k_rel_fin(const float* __restrict__ part, const float* __restrict__ b1,
                          const float* __restrict__ w2, const float* __restrict__ b2,
                          float* __restrict__ out) {
    int bq = blockIdx.x, tid = threadIdx.x;
    float a = 0.f;
    #pragma unroll
    for (int s = 0; s < 3; ++s) {
        int col = tid + s * 256;
        float sum = 0.f;
        #pragma unroll
        for (int ks = 0; ks < 8; ++ks) sum += part[((size_t)ks * BQ_ + bq) * D_ + col];
        float h = fmaxf(sum + b1[col], 0.f);
        a += h * w2[col];
    }
    __shared__ float red[256];
    red[tid] = a; __syncthreads();
    for (int off = 128; off >= 1; off >>= 1) {
        if (tid < off) red[tid] += red[tid + off];
        __syncthreads();
    }
    if (tid == 0) out[bq] = red[0] + b2[0];
}

extern "C" void kernel_launch(void* const* d_in, const int* in_sizes, int n_in,
                              void* d_out, int out_size, void* d_ws, size_t ws_size,
                              hipStream_t stream) {
    (void)in_sizes; (void)n_in; (void)out_size; (void)ws_size;
    const float* semb  = (const float*)d_in[0];
    const float* qemb  = (const float*)d_in[1];
    const float* smask = (const float*)d_in[2];
    const float* qmask = (const float*)d_in[3];
    const float* label = (const float*)d_in[4];
    const float* projw = (const float*)d_in[5];
    const float* projb = (const float*)d_in[6];
    const float* relw1 = (const float*)d_in[7];
    const float* relb1 = (const float*)d_in[8];
    const float* relw2 = (const float*)d_in[9];
    const float* relb2 = (const float*)d_in[10];

    char* ws = (char*)d_ws;
    u16*   qemb_bf   = (u16*)  (ws + 0);           // 7,864,320
    u16*   projw_bf  = (u16*)  (ws + 7864320);     // 4,718,592
    u16*   relw1_bf  = (u16*)  (ws + 12582912);    // 4,718,592
    float* proto_shot= (float*)(ws + 17301504);    // 768,000
    float* proto_f32 = (float*)(ws + 18069504);    // 153,600
    u16*   proto_bf  = (u16*)  (ws + 18223104);    // 76,800
    float* qssum     = (float*)(ws + 18299904);    // 896
    u16*   sup_ws    = (u16*)  (ws + 18300800);    // 1,536,000
    float* p2m_ws    = (float*)(ws + 19836800);    // 512,000
    u16*   pw2_ws    = (u16*)  (ws + 20348800);    // 76,800
    u16*   sw2_ws    = (u16*)  (ws + 20425600);    // 1,536,000
    u16*   cat_ws    = (u16*)  (ws + 21961600);    // 1,228,800
    u16*   g1_ws     = (u16*)  (ws + 23190400);    // 8,060,928
    float* part_ws   = (float*)(ws + 31251328);    // 4,915,200
    u16*   qf_ws     = (u16*)  (ws + 36166528);    // 200*144*1536*2 = 88,473,600
    // total 124,640,128 bytes

    k_convert3<<<2048, 256, 0, stream>>>(qemb, projw, relw1, qemb_bf, projw_bf, relw1_bf);
    k_proto_shot<<<BNK_, 256, 0, stream>>>(label, smask, semb, proto_shot);
    k_proto_mean<<<150, 256, 0, stream>>>(proto_shot, proto_f32, proto_bf);
    k_attn<<<BQ_, 256, 0, stream>>>(qemb, qmask, proto_f32, qf_ws, sup_ws, p2m_ws, qssum);
    k_gemm_g1<<<dim3(6, 41), 256, 0, stream>>>(qemb_bf, proto_bf, projw_bf, g1_ws);
    k_gemm_w2<<<dim3(6, 9), 256, 0, stream>>>(sup_ws, proto_bf, projw_bf, sw2_ws, pw2_ws);
    k_gemm_q<<<1200, 256, 0, stream>>>(qf_ws, projw_bf, projb, g1_ws, pw2_ws, sw2_ws,
                                       p2m_ws, qssum, cat_ws);
    k_relmlp<<<dim3(6, 4, 8), 256, 0, stream>>>(cat_ws, relw1_bf, part_ws);
    k_rel_fin<<<BQ_, 256, 0, stream>>>(part_ws, relb1, relw2, relb2, (float*)d_out);
}